// Round 8
// baseline (284.805 us; speedup 1.0000x reference)
//
#include <hip/hip_runtime.h>
#include <hip/hip_bf16.h>

// Problem constants (fixed by the reference)
#define E    256
#define NH   8
#define NL   3
#define NP   4
#define HD   32
#define LQ   13125   // = Lv = 10000 + 2500 + 625

typedef short bf16x8 __attribute__((ext_vector_type(8)));
typedef float f32x4  __attribute__((ext_vector_type(4)));

// round-to-nearest-even fp32 -> bf16 (as ushort bits)
__device__ __forceinline__ ushort f2bf(float x) {
  uint u = __float_as_uint(x);
  uint r = (u + 0x7fffu + ((u >> 16) & 1u)) >> 16;
  return (ushort)r;
}
__device__ __forceinline__ float bf2f(ushort u) {
  return __uint_as_float((uint)u << 16);
}
// two bf16 packed in a dword -> two floats (2 bit-ops, no shifts of data path)
__device__ __forceinline__ float2 bfpair(uint u) {
  float2 f;
  f.x = __uint_as_float(u << 16);
  f.y = __uint_as_float(u & 0xffff0000u);
  return f;
}

__device__ __forceinline__ void gl_lds16(const ushort* g, ushort* l) {
  __builtin_amdgcn_global_load_lds(
      (const __attribute__((address_space(1))) void*)g,
      (__attribute__((address_space(3))) void*)l, 16, 0, 0);
}

// ---------------------------------------------------------------------------
// fp32 [M][256] -> bf16 (hi only), vectorized.
// ---------------------------------------------------------------------------
__global__ __launch_bounds__(256) void convertA_hi(
    const float* __restrict__ A, ushort* __restrict__ hi, int n4) {
  const int i = blockIdx.x * 256 + threadIdx.x;
  if (i >= n4) return;
  const float4 a = ((const float4*)A)[i];
  ushort4 h;
  h.x = f2bf(a.x); h.y = f2bf(a.y); h.z = f2bf(a.z); h.w = f2bf(a.w);
  ((ushort4*)hi)[i] = h;
}

// ---------------------------------------------------------------------------
// Single-phase bf16 MFMA GEMM, 2-phase prefetch pipeline (T3 minimum):
//   C = A @ B^T + bias.  A: [M][256] bf16.  B: [N][256] bf16 (transposed).
// Tile 128x128, 4 waves (2x2), BK=32; double-buffered LDS (2x16KB) staged via
// global_load_lds width-16.  Stage(t+1) issued before compute(t); one
// vmcnt-draining __syncthreads per K-step.
// OUT_MODE 0: fp32 C[M][N].  OUT_MODE 1: bf16 head-major value layout.
// ---------------------------------------------------------------------------
template <int OUT_MODE>
__global__ __launch_bounds__(256) void gemm_bf16(
    const ushort* __restrict__ A_, const ushort* __restrict__ B_,
    const float* __restrict__ bias, float* __restrict__ C,
    ushort* __restrict__ Cbf, int M, int N) {
  __shared__ ushort As[2][4096];
  __shared__ ushort Bs[2][4096];
  const int tid = threadIdx.x;
  const int lane = tid & 63;
  const int wid = tid >> 6;
  const int wm = wid >> 1, wn = wid & 1;
  const int r0 = blockIdx.x * 128;
  const int c0 = blockIdx.y * 128;
  const int l15 = lane & 15;
  const int lhi = lane >> 4;
  const int srow = lane >> 2;        // row within 16-row chunk
  const int skoff = (lane & 3) * 8;  // ushort offset within 32-elem row

  f32x4 acc[4][4] = {};

  auto stage = [&](int buf, int kk) {
#pragma unroll
    for (int j = 0; j < 2; ++j) {
      const int c = wid + j * 4;
      const int arow = min(r0 + c * 16 + srow, M - 1);
      const int brow = min(c0 + c * 16 + srow, N - 1);
      gl_lds16(A_ + (size_t)arow * 256 + kk + skoff, &As[buf][c * 512]);
      gl_lds16(B_ + (size_t)brow * 256 + kk + skoff, &Bs[buf][c * 512]);
    }
  };

  stage(0, 0);
  __syncthreads();  // drain prologue stage

#pragma unroll
  for (int t = 0; t < 8; ++t) {
    const int cur = t & 1;
    if (t + 1 < 8) stage(cur ^ 1, (t + 1) * 32);  // in flight during compute

    bf16x8 af[4], bf[4];
#pragma unroll
    for (int mi = 0; mi < 4; ++mi)
      af[mi] = *(const bf16x8*)&As[cur][(wm * 64 + mi * 16 + l15) * 32 + lhi * 8];
#pragma unroll
    for (int ni = 0; ni < 4; ++ni)
      bf[ni] = *(const bf16x8*)&Bs[cur][(wn * 64 + ni * 16 + l15) * 32 + lhi * 8];
#pragma unroll
    for (int mi = 0; mi < 4; ++mi)
#pragma unroll
      for (int ni = 0; ni < 4; ++ni)
        acc[mi][ni] = __builtin_amdgcn_mfma_f32_16x16x32_bf16(
            af[mi], bf[ni], acc[mi][ni], 0, 0, 0);

    if (t + 1 < 8) __syncthreads();  // vmcnt(0)+lgkm drain: next buf ready
  }

  // epilogue: C/D layout col=lane&15, row=(lane>>4)*4+reg (m89-verified)
#pragma unroll
  for (int ni = 0; ni < 4; ++ni) {
    const int col = c0 + wn * 64 + ni * 16 + l15;
    if (col >= N) continue;
    const float bb = bias[col];
#pragma unroll
    for (int mi = 0; mi < 4; ++mi) {
      const int rowb = r0 + wm * 64 + mi * 16 + lhi * 4;
#pragma unroll
      for (int r = 0; r < 4; ++r) {
        const int row = rowb + r;
        if (row >= M) continue;
        if (OUT_MODE == 0) {
          C[(size_t)row * N + col] = acc[mi][ni][r] + bb;
        } else {
          const int bidx = row / LQ, pos = row - bidx * LQ;
          const int h = col >> 5, d = col & 31;
          Cbf[((size_t)(bidx * NH + h) * LQ + pos) * HD + d] =
              f2bf(acc[mi][ni][r] + bb);
        }
      }
    }
  }
}

// ---------------------------------------------------------------------------
// One-shot weight prep: transpose + bf16 (hi only).
// ---------------------------------------------------------------------------
__global__ __launch_bounds__(256) void convert_W(
    const float* __restrict__ Wv, const float* __restrict__ Woff,
    const float* __restrict__ Watt, const float* __restrict__ Wo,
    const float* __restrict__ boff, const float* __restrict__ batt,
    ushort* __restrict__ WvT, ushort* __restrict__ WcT,
    ushort* __restrict__ WoT, float* __restrict__ bias288) {
  const int t = blockIdx.x * 256 + threadIdx.x;
  if (t < 256 * 256) {
    const int n = t >> 8, k = t & 255;
    WvT[t] = f2bf(Wv[k * 256 + n]);
    WoT[t] = f2bf(Wo[k * 256 + n]);
  }
  if (t < 288 * 256) {
    const int n = t >> 8, k = t & 255;
    const float w = (n < 192) ? Woff[k * 192 + n] : Watt[k * 96 + (n - 192)];
    WcT[t] = f2bf(w);
  }
  if (t < 288) bias288[t] = (t < 192) ? boff[t] : batt[t - 192];
}

// ---------------------------------------------------------------------------
// finalize_pack: raw[M][288] (fp32 GEMM output) -> packed bilinear samples,
// IN PLACE.  One thread per (g,h): softmax over 12 logits, pixel coords,
// clamp/validity, pre-multiplied corner weights.  Packed record per sample
// (12B): d0 = idx00 | meta<<16  (meta = dx | dyW<<1), d1 = w00|w01 (bf16x2),
// d2 = w10|w11.  Per (g,h): 12 samples x 3 dwords = 36 dwords = 144B; per g:
// 8*144 = 1152B = exactly the 288 fp32 of raw -> in-place rewrite.
// Read phase -> __syncthreads -> write phase (block owns its 32 g rows).
// ---------------------------------------------------------------------------
__global__ __launch_bounds__(256) void finalize_pack(
    float* __restrict__ raw, const float* __restrict__ ref, int M) {
  const int tid = threadIdx.x;
  const int g = blockIdx.x * 32 + (tid >> 3);
  const int h = tid & 7;
  const bool active = (g < M);

  uint out[36];
  if (active) {
    const float* rg = raw + (size_t)g * 288;
    float xy[24], lg[12];
    const float4* c4 = (const float4*)(rg + h * 24);
#pragma unroll
    for (int i = 0; i < 6; ++i) {
      float4 t = c4[i];
      xy[4 * i + 0] = t.x; xy[4 * i + 1] = t.y;
      xy[4 * i + 2] = t.z; xy[4 * i + 3] = t.w;
    }
    const float4* a4 = (const float4*)(rg + 192 + h * 12);
#pragma unroll
    for (int i = 0; i < 3; ++i) {
      float4 t = a4[i];
      lg[4 * i + 0] = t.x; lg[4 * i + 1] = t.y;
      lg[4 * i + 2] = t.z; lg[4 * i + 3] = t.w;
    }
    float rx[3], ry[3];
#pragma unroll
    for (int l = 0; l < 3; ++l) {
      rx[l] = ref[(size_t)g * 6 + l * 2 + 0];
      ry[l] = ref[(size_t)g * 6 + l * 2 + 1];
    }
    // softmax
    float m = lg[0];
#pragma unroll
    for (int j = 1; j < 12; ++j) m = fmaxf(m, lg[j]);
    float e[12], s = 0.f;
#pragma unroll
    for (int j = 0; j < 12; ++j) { e[j] = __expf(lg[j] - m); s += e[j]; }
    const float inv = 1.f / s;

    const float S_[3] = {100.f, 50.f, 25.f};
    const int Wl_[3] = {100, 50, 25};
#pragma unroll
    for (int l = 0; l < 3; ++l) {
      const int Wl = Wl_[l];
#pragma unroll
      for (int p = 0; p < 4; ++p) {
        const int j = l * 4 + p;
        const float x = rx[l] * S_[l] + xy[l * 8 + p * 2 + 0] - 0.5f;
        const float y = ry[l] * S_[l] + xy[l * 8 + p * 2 + 1] - 0.5f;
        const float w = e[j] * inv;
        const float fx = floorf(x), fy = floorf(y);
        const int x0 = (int)fx, y0 = (int)fy;
        const float wx1 = x - fx, wy1 = y - fy;
        const float wx0 = 1.f - wx1, wy0 = 1.f - wy1;
        const int x0c = min(max(x0, 0), Wl - 1);
        const int x1c = min(max(x0 + 1, 0), Wl - 1);
        const int y0c = min(max(y0, 0), Wl - 1);
        const int y1c = min(max(y0 + 1, 0), Wl - 1);
        const float vx0 = (x0 >= 0 && x0 < Wl) ? wx0 : 0.f;
        const float vx1 = (x0 + 1 >= 0 && x0 + 1 < Wl) ? wx1 : 0.f;
        const float vy0 = (y0 >= 0 && y0 < Wl) ? wy0 : 0.f;
        const float vy1 = (y0 + 1 >= 0 && y0 + 1 < Wl) ? wy1 : 0.f;
        const int idx00 = y0c * Wl + x0c;
        const uint meta = (uint)(x1c - x0c) | ((uint)((y1c - y0c) * Wl) << 1);
        out[j * 3 + 0] = (uint)idx00 | (meta << 16);
        out[j * 3 + 1] = (uint)f2bf(w * vy0 * vx0) | ((uint)f2bf(w * vy0 * vx1) << 16);
        out[j * 3 + 2] = (uint)f2bf(w * vy1 * vx0) | ((uint)f2bf(w * vy1 * vx1) << 16);
      }
    }
  }
  __syncthreads();  // all reads of this block's rows complete before rewrite
  if (active) {
    uint4* o4 = (uint4*)((uint*)raw + (size_t)g * 288 + h * 36);
#pragma unroll
    for (int i = 0; i < 9; ++i)
      o4[i] = make_uint4(out[i * 4 + 0], out[i * 4 + 1],
                         out[i * 4 + 2], out[i * 4 + 3]);
  }
}

// ---------------------------------------------------------------------------
// Bilinear sampling from packed records.  8 lanes per (g,h), lane owns 4
// channels.  Per sample: unpack + 4 gathers (ushort4) + 16 cvt + 16 FMA —
// no floor/clamp/compare chain (done once in finalize_pack).
// vbf layout: [(b*8+h)][pos][32] bf16.  Output mid: bf16 [g][256].
// ---------------------------------------------------------------------------
__global__ __launch_bounds__(256) void deform_packed(
    const ushort* __restrict__ vbf, const uint* __restrict__ samp,
    ushort* __restrict__ mid, int M) {
  const int tid = threadIdx.x;
  const int gidx = blockIdx.x * 32 + (tid >> 3);
  if (gidx >= M * NH) return;
  const int d4 = (tid & 7) << 2;
  const int g = gidx >> 3;
  const int h = gidx & 7;
  const int b = g / LQ;

  const uint4* sp = (const uint4*)(samp + (size_t)g * 288 + h * 36);
  const ushort* vb = vbf + ((size_t)(b * NH + h) * LQ) * HD + d4;

  const int loff_[3] = {0, 10000, 12500};
  float4 acc = make_float4(0.f, 0.f, 0.f, 0.f);

#pragma unroll
  for (int l = 0; l < NL; ++l) {
    const ushort* vl = vb + (size_t)loff_[l] * HD;
    const uint4 s0 = sp[l * 3 + 0];
    const uint4 s1 = sp[l * 3 + 1];
    const uint4 s2 = sp[l * 3 + 2];
    const uint sd[12] = {s0.x, s0.y, s0.z, s0.w,
                         s1.x, s1.y, s1.z, s1.w,
                         s2.x, s2.y, s2.z, s2.w};
#pragma unroll
    for (int p = 0; p < NP; ++p) {
      const uint d0 = sd[p * 3 + 0];
      const uint d1 = sd[p * 3 + 1];
      const uint d2 = sd[p * 3 + 2];
      const int idx00 = (int)(d0 & 0xffffu);
      const uint meta = d0 >> 16;
      const int dx = (int)(meta & 1u);
      const int dyW = (int)(meta >> 1);
      const float2 wA = bfpair(d1);  // w00, w01
      const float2 wB = bfpair(d2);  // w10, w11
      const ushort* p00 = vl + (size_t)idx00 * HD;
      const ushort4 c00 = *(const ushort4*)(p00);
      const ushort4 c01 = *(const ushort4*)(p00 + dx * HD);
      const ushort4 c10 = *(const ushort4*)(p00 + dyW * HD);
      const ushort4 c11 = *(const ushort4*)(p00 + (dyW + dx) * HD);
      acc.x += wA.x * bf2f(c00.x) + wA.y * bf2f(c01.x) + wB.x * bf2f(c10.x) + wB.y * bf2f(c11.x);
      acc.y += wA.x * bf2f(c00.y) + wA.y * bf2f(c01.y) + wB.x * bf2f(c10.y) + wB.y * bf2f(c11.y);
      acc.z += wA.x * bf2f(c00.z) + wA.y * bf2f(c01.z) + wB.x * bf2f(c10.z) + wB.y * bf2f(c11.z);
      acc.w += wA.x * bf2f(c00.w) + wA.y * bf2f(c01.w) + wB.x * bf2f(c10.w) + wB.y * bf2f(c11.w);
    }
  }
  ushort4 o;
  o.x = f2bf(acc.x); o.y = f2bf(acc.y); o.z = f2bf(acc.z); o.w = f2bf(acc.w);
  *(ushort4*)&mid[(size_t)g * E + h * HD + d4] = o;
}

// ---------------------------------------------------------------------------
extern "C" void kernel_launch(void* const* d_in, const int* in_sizes, int n_in,
                              void* d_out, int out_size, void* d_ws, size_t ws_size,
                              hipStream_t stream) {
  const float* query = (const float*)d_in[0];
  const float* refpt = (const float*)d_in[1];
  const float* value = (const float*)d_in[2];
  const float* Wv   = (const float*)d_in[4];
  const float* bv   = (const float*)d_in[5];
  const float* Woff = (const float*)d_in[6];
  const float* boff = (const float*)d_in[7];
  const float* Watt = (const float*)d_in[8];
  const float* batt = (const float*)d_in[9];
  const float* Wo   = (const float*)d_in[10];
  const float* bo   = (const float*)d_in[11];

  const int M = in_sizes[0] / E;  // B * Lq = 52500

  // workspace layout (~90 MB)
  float* wsf   = (float*)d_ws;
  float* raw   = wsf;                         // M*288 floats (later: packed samples)
  float* b288  = raw + (size_t)M * 288;       // 288
  ushort* mid  = (ushort*)(b288 + 288);       // M*256 ushorts
  ushort* vbf  = mid + (size_t)M * 256;       // M*256 ushorts
  ushort* wvT  = vbf + (size_t)M * 256;       // 65536
  ushort* woT  = wvT + 65536;                 // 65536
  ushort* wcT  = woT + 65536;                 // 73728

  // bf16 A-operands live in d_out (2 x M*256 ushorts = exact fit).
  // d_out is dead until the final GEMM writes it (by which time both are dead).
  ushort* vhi = (ushort*)d_out;
  ushort* qhi = vhi + (size_t)M * 256;

  const int gridM = (M + 127) / 128;
  const int convGrid = (M * 64 + 255) / 256;

  // 0. weight prep (bf16 hi only)
  convert_W<<<288, 256, 0, stream>>>(Wv, Woff, Watt, Wo, boff, batt,
                                     wvT, wcT, woT, b288);
  // 1a. value -> bf16
  convertA_hi<<<convGrid, 256, 0, stream>>>(value, vhi, M * 64);
  // 1b. value projection -> vbf (bf16, head-major)
  gemm_bf16<1><<<dim3(gridM, 2), 256, 0, stream>>>(
      vhi, wvT, bv, nullptr, vbf, M, 256);
  // 2a. query -> bf16
  convertA_hi<<<convGrid, 256, 0, stream>>>(query, qhi, M * 64);
  // 2b. offsets+attention raw projection -> raw (fp32)
  gemm_bf16<0><<<dim3(gridM, 3), 256, 0, stream>>>(
      qhi, wcT, b288, raw, nullptr, M, 288);
  // 3. softmax + coords + bilinear setup, packed in place on raw
  finalize_pack<<<(M + 31) / 32, 256, 0, stream>>>(raw, refpt, M);
  // 4. deformable bilinear sampling from packed records -> mid (bf16)
  deform_packed<<<(M * NH + 31) / 32, 256, 0, stream>>>(
      vbf, (const uint*)raw, mid, M);
  // 5. output projection: mid (bf16) @ Wo -> d_out (fp32)
  gemm_bf16<0><<<dim3(gridM, 2), 256, 0, stream>>>(
      mid, woT, bo, (float*)d_out, nullptr, M, 256);
}

// Round 9
// 276.818 us; speedup vs baseline: 1.0289x; 1.0289x over previous
//
#include <hip/hip_runtime.h>
#include <hip/hip_bf16.h>

// Problem constants (fixed by the reference)
#define E    256
#define NH   8
#define NL   3
#define NP   4
#define HD   32
#define LQ   13125   // = Lv = 10000 + 2500 + 625

typedef short bf16x8 __attribute__((ext_vector_type(8)));
typedef float f32x4  __attribute__((ext_vector_type(4)));

// round-to-nearest-even fp32 -> bf16 (as ushort bits)
__device__ __forceinline__ ushort f2bf(float x) {
  uint u = __float_as_uint(x);
  uint r = (u + 0x7fffu + ((u >> 16) & 1u)) >> 16;
  return (ushort)r;
}
__device__ __forceinline__ float bf2f(ushort u) {
  return __uint_as_float((uint)u << 16);
}
__device__ __forceinline__ float2 bfpair(uint u) {
  float2 f;
  f.x = __uint_as_float(u << 16);
  f.y = __uint_as_float(u & 0xffff0000u);
  return f;
}

__device__ __forceinline__ void gl_lds16(const ushort* g, ushort* l) {
  __builtin_amdgcn_global_load_lds(
      (const __attribute__((address_space(1))) void*)g,
      (__attribute__((address_space(3))) void*)l, 16, 0, 0);
}

// ---------------------------------------------------------------------------
// fp32 [M][256] -> bf16 (hi only), vectorized.
// ---------------------------------------------------------------------------
__global__ __launch_bounds__(256) void convertA_hi(
    const float* __restrict__ A, ushort* __restrict__ hi, int n4) {
  const int i = blockIdx.x * 256 + threadIdx.x;
  if (i >= n4) return;
  const float4 a = ((const float4*)A)[i];
  ushort4 h;
  h.x = f2bf(a.x); h.y = f2bf(a.y); h.z = f2bf(a.z); h.w = f2bf(a.w);
  ((ushort4*)hi)[i] = h;
}

// ---------------------------------------------------------------------------
// Single-phase bf16 MFMA GEMM (round-7 proven, single-buffer m97 structure):
//   C = A @ B^T + bias.  A: [M][256] bf16.  B: [N][256] bf16 (transposed).
// Tile 128x128, 4 waves (2x2), BK=32; LDS 2 linear tiles staged via
// global_load_lds width-16; 16 MFMAs per barrier-pair, 8 K-steps.
// OUT_MODE 0: fp32 C[M][N].  OUT_MODE 1: bf16 head-major value layout.
// ---------------------------------------------------------------------------
template <int OUT_MODE>
__global__ __launch_bounds__(256) void gemm_bf16(
    const ushort* __restrict__ A_, const ushort* __restrict__ B_,
    const float* __restrict__ bias, float* __restrict__ C,
    ushort* __restrict__ Cbf, int M, int N) {
  __shared__ ushort As[4096];
  __shared__ ushort Bs[4096];
  const int tid = threadIdx.x;
  const int lane = tid & 63;
  const int wid = tid >> 6;
  const int wm = wid >> 1, wn = wid & 1;
  const int r0 = blockIdx.x * 128;
  const int c0 = blockIdx.y * 128;
  const int l15 = lane & 15;
  const int lhi = lane >> 4;
  const int srow = lane >> 2;        // row within 16-row chunk
  const int skoff = (lane & 3) * 8;  // ushort offset within 32-elem row

  f32x4 acc[4][4] = {};

  for (int kk = 0; kk < 256; kk += 32) {
#pragma unroll
    for (int j = 0; j < 2; ++j) {
      const int c = wid + j * 4;
      const int arow = min(r0 + c * 16 + srow, M - 1);
      const int brow = min(c0 + c * 16 + srow, N - 1);
      gl_lds16(A_ + (size_t)arow * 256 + kk + skoff, As + c * 512);
      gl_lds16(B_ + (size_t)brow * 256 + kk + skoff, Bs + c * 512);
    }
    __syncthreads();  // drains vmcnt (global_load_lds) before LDS reads

    bf16x8 af[4], bf[4];
#pragma unroll
    for (int mi = 0; mi < 4; ++mi)
      af[mi] = *(const bf16x8*)&As[(wm * 64 + mi * 16 + l15) * 32 + lhi * 8];
#pragma unroll
    for (int ni = 0; ni < 4; ++ni)
      bf[ni] = *(const bf16x8*)&Bs[(wn * 64 + ni * 16 + l15) * 32 + lhi * 8];
#pragma unroll
    for (int mi = 0; mi < 4; ++mi)
#pragma unroll
      for (int ni = 0; ni < 4; ++ni)
        acc[mi][ni] = __builtin_amdgcn_mfma_f32_16x16x32_bf16(
            af[mi], bf[ni], acc[mi][ni], 0, 0, 0);
    __syncthreads();  // protect LDS from next-iteration staging
  }

  // epilogue: C/D layout col=lane&15, row=(lane>>4)*4+reg (m89-verified)
#pragma unroll
  for (int ni = 0; ni < 4; ++ni) {
    const int col = c0 + wn * 64 + ni * 16 + l15;
    if (col >= N) continue;
    const float bb = bias[col];
#pragma unroll
    for (int mi = 0; mi < 4; ++mi) {
      const int rowb = r0 + wm * 64 + mi * 16 + lhi * 4;
#pragma unroll
      for (int r = 0; r < 4; ++r) {
        const int row = rowb + r;
        if (row >= M) continue;
        if (OUT_MODE == 0) {
          C[(size_t)row * N + col] = acc[mi][ni][r] + bb;
        } else {
          const int bidx = row / LQ, pos = row - bidx * LQ;
          const int h = col >> 5, d = col & 31;
          Cbf[((size_t)(bidx * NH + h) * LQ + pos) * HD + d] =
              f2bf(acc[mi][ni][r] + bb);
        }
      }
    }
  }
}

// ---------------------------------------------------------------------------
// One-shot weight prep: transpose + bf16 (hi only).
// ---------------------------------------------------------------------------
__global__ __launch_bounds__(256) void convert_W(
    const float* __restrict__ Wv, const float* __restrict__ Woff,
    const float* __restrict__ Watt, const float* __restrict__ Wo,
    const float* __restrict__ boff, const float* __restrict__ batt,
    ushort* __restrict__ WvT, ushort* __restrict__ WcT,
    ushort* __restrict__ WoT, float* __restrict__ bias288) {
  const int t = blockIdx.x * 256 + threadIdx.x;
  if (t < 256 * 256) {
    const int n = t >> 8, k = t & 255;
    WvT[t] = f2bf(Wv[k * 256 + n]);
    WoT[t] = f2bf(Wo[k * 256 + n]);
  }
  if (t < 288 * 256) {
    const int n = t >> 8, k = t & 255;
    const float w = (n < 192) ? Woff[k * 192 + n] : Watt[k * 96 + (n - 192)];
    WcT[t] = f2bf(w);
  }
  if (t < 288) bias288[t] = (t < 192) ? boff[t] : batt[t - 192];
}

// ---------------------------------------------------------------------------
// finalize_pack: raw[M][288] (fp32 GEMM output) -> packed bilinear samples,
// IN PLACE.  One thread per (g,h): softmax, pixel coords, clamp/validity,
// pre-multiplied bf16 corner weights.  12B per sample:
//   d0 = idx00 | meta<<16 (meta = dx | dyW<<1), d1 = w00|w01, d2 = w10|w11.
// Per g: 8*144B = 1152B = the 288 fp32 of raw -> exact in-place rewrite.
// ---------------------------------------------------------------------------
__global__ __launch_bounds__(256) void finalize_pack(
    float* __restrict__ raw, const float* __restrict__ ref, int M) {
  const int tid = threadIdx.x;
  const int g = blockIdx.x * 32 + (tid >> 3);
  const int h = tid & 7;
  const bool active = (g < M);

  uint out[36];
  if (active) {
    const float* rg = raw + (size_t)g * 288;
    float xy[24], lg[12];
    const float4* c4 = (const float4*)(rg + h * 24);
#pragma unroll
    for (int i = 0; i < 6; ++i) {
      float4 t = c4[i];
      xy[4 * i + 0] = t.x; xy[4 * i + 1] = t.y;
      xy[4 * i + 2] = t.z; xy[4 * i + 3] = t.w;
    }
    const float4* a4 = (const float4*)(rg + 192 + h * 12);
#pragma unroll
    for (int i = 0; i < 3; ++i) {
      float4 t = a4[i];
      lg[4 * i + 0] = t.x; lg[4 * i + 1] = t.y;
      lg[4 * i + 2] = t.z; lg[4 * i + 3] = t.w;
    }
    float rx[3], ry[3];
#pragma unroll
    for (int l = 0; l < 3; ++l) {
      rx[l] = ref[(size_t)g * 6 + l * 2 + 0];
      ry[l] = ref[(size_t)g * 6 + l * 2 + 1];
    }
    float m = lg[0];
#pragma unroll
    for (int j = 1; j < 12; ++j) m = fmaxf(m, lg[j]);
    float e[12], s = 0.f;
#pragma unroll
    for (int j = 0; j < 12; ++j) { e[j] = __expf(lg[j] - m); s += e[j]; }
    const float inv = 1.f / s;

    const float S_[3] = {100.f, 50.f, 25.f};
    const int Wl_[3] = {100, 50, 25};
#pragma unroll
    for (int l = 0; l < 3; ++l) {
      const int Wl = Wl_[l];
#pragma unroll
      for (int p = 0; p < 4; ++p) {
        const int j = l * 4 + p;
        const float x = rx[l] * S_[l] + xy[l * 8 + p * 2 + 0] - 0.5f;
        const float y = ry[l] * S_[l] + xy[l * 8 + p * 2 + 1] - 0.5f;
        const float w = e[j] * inv;
        const float fx = floorf(x), fy = floorf(y);
        const int x0 = (int)fx, y0 = (int)fy;
        const float wx1 = x - fx, wy1 = y - fy;
        const float wx0 = 1.f - wx1, wy0 = 1.f - wy1;
        const int x0c = min(max(x0, 0), Wl - 1);
        const int x1c = min(max(x0 + 1, 0), Wl - 1);
        const int y0c = min(max(y0, 0), Wl - 1);
        const int y1c = min(max(y0 + 1, 0), Wl - 1);
        const float vx0 = (x0 >= 0 && x0 < Wl) ? wx0 : 0.f;
        const float vx1 = (x0 + 1 >= 0 && x0 + 1 < Wl) ? wx1 : 0.f;
        const float vy0 = (y0 >= 0 && y0 < Wl) ? wy0 : 0.f;
        const float vy1 = (y0 + 1 >= 0 && y0 + 1 < Wl) ? wy1 : 0.f;
        const int idx00 = y0c * Wl + x0c;
        const uint meta = (uint)(x1c - x0c) | ((uint)((y1c - y0c) * Wl) << 1);
        out[j * 3 + 0] = (uint)idx00 | (meta << 16);
        out[j * 3 + 1] = (uint)f2bf(w * vy0 * vx0) | ((uint)f2bf(w * vy0 * vx1) << 16);
        out[j * 3 + 2] = (uint)f2bf(w * vy1 * vx0) | ((uint)f2bf(w * vy1 * vx1) << 16);
      }
    }
  }
  __syncthreads();  // all reads of this block's rows complete before rewrite
  if (active) {
    uint4* o4 = (uint4*)((uint*)raw + (size_t)g * 288 + h * 36);
#pragma unroll
    for (int i = 0; i < 9; ++i)
      o4[i] = make_uint4(out[i * 4 + 0], out[i * 4 + 1],
                         out[i * 4 + 2], out[i * 4 + 3]);
  }
}

// ---------------------------------------------------------------------------
// Bilinear sampling from packed records, XCD-partitioned by (b,h) pair.
// Block = 32 queries x ONE (b,h) pair (8 lanes/query, 4 channels/lane).
// blockIdx.x = qchunk*32 + pair  ==>  with round-robin blockIdx%8 -> XCD,
// pair p always lands on XCD p%8; per-XCD live working set = 4 pairs x
// 0.84 MB = 3.36 MB < 4 MB L2 -> gathers become L2 hits.
// vbf layout: [(b*8+h)][pos][32] bf16 (pair-major -- matches partitioning).
// ---------------------------------------------------------------------------
__global__ __launch_bounds__(256) void deform_packed(
    const ushort* __restrict__ vbf, const uint* __restrict__ samp,
    ushort* __restrict__ mid, int nq) {
  const int tid = threadIdx.x;
  const int pair = blockIdx.x & 31;          // b*8 + h
  const int qc = blockIdx.x >> 5;
  const int q = qc * 32 + (tid >> 3);        // query within batch
  if (q >= nq) return;
  const int d4 = (tid & 7) << 2;
  const int h = pair & 7;
  const int b = pair >> 3;
  const int g = b * nq + q;

  const uint4* sp = (const uint4*)(samp + (size_t)g * 288 + h * 36);
  const ushort* vb = vbf + ((size_t)pair * nq) * HD + d4;

  const int loff_[3] = {0, 10000, 12500};
  float4 acc = make_float4(0.f, 0.f, 0.f, 0.f);

#pragma unroll
  for (int l = 0; l < NL; ++l) {
    const ushort* vl = vb + (size_t)loff_[l] * HD;
    const uint4 s0 = sp[l * 3 + 0];
    const uint4 s1 = sp[l * 3 + 1];
    const uint4 s2 = sp[l * 3 + 2];
    const uint sd[12] = {s0.x, s0.y, s0.z, s0.w,
                         s1.x, s1.y, s1.z, s1.w,
                         s2.x, s2.y, s2.z, s2.w};
#pragma unroll
    for (int p = 0; p < NP; ++p) {
      const uint d0 = sd[p * 3 + 0];
      const uint d1 = sd[p * 3 + 1];
      const uint d2 = sd[p * 3 + 2];
      const int idx00 = (int)(d0 & 0xffffu);
      const uint meta = d0 >> 16;
      const int dx = (int)(meta & 1u);
      const int dyW = (int)(meta >> 1);
      const float2 wA = bfpair(d1);  // w00, w01
      const float2 wB = bfpair(d2);  // w10, w11
      const ushort* p00 = vl + (size_t)idx00 * HD;
      const ushort4 c00 = *(const ushort4*)(p00);
      const ushort4 c01 = *(const ushort4*)(p00 + dx * HD);
      const ushort4 c10 = *(const ushort4*)(p00 + dyW * HD);
      const ushort4 c11 = *(const ushort4*)(p00 + (dyW + dx) * HD);
      acc.x += wA.x * bf2f(c00.x) + wA.y * bf2f(c01.x) + wB.x * bf2f(c10.x) + wB.y * bf2f(c11.x);
      acc.y += wA.x * bf2f(c00.y) + wA.y * bf2f(c01.y) + wB.x * bf2f(c10.y) + wB.y * bf2f(c11.y);
      acc.z += wA.x * bf2f(c00.z) + wA.y * bf2f(c01.z) + wB.x * bf2f(c10.z) + wB.y * bf2f(c11.z);
      acc.w += wA.x * bf2f(c00.w) + wA.y * bf2f(c01.w) + wB.x * bf2f(c10.w) + wB.y * bf2f(c11.w);
    }
  }
  ushort4 o;
  o.x = f2bf(acc.x); o.y = f2bf(acc.y); o.z = f2bf(acc.z); o.w = f2bf(acc.w);
  *(ushort4*)&mid[(size_t)g * E + h * HD + d4] = o;
}

// ---------------------------------------------------------------------------
extern "C" void kernel_launch(void* const* d_in, const int* in_sizes, int n_in,
                              void* d_out, int out_size, void* d_ws, size_t ws_size,
                              hipStream_t stream) {
  const float* query = (const float*)d_in[0];
  const float* refpt = (const float*)d_in[1];
  const float* value = (const float*)d_in[2];
  const float* Wv   = (const float*)d_in[4];
  const float* bv   = (const float*)d_in[5];
  const float* Woff = (const float*)d_in[6];
  const float* boff = (const float*)d_in[7];
  const float* Watt = (const float*)d_in[8];
  const float* batt = (const float*)d_in[9];
  const float* Wo   = (const float*)d_in[10];
  const float* bo   = (const float*)d_in[11];

  const int M = in_sizes[0] / E;  // B * Lq = 52500
  const int nq = LQ;              // queries per batch
  const int nb = M / nq;          // B = 4

  // workspace layout (~90 MB)
  float* wsf   = (float*)d_ws;
  float* raw   = wsf;                         // M*288 floats (later: packed samples)
  float* b288  = raw + (size_t)M * 288;       // 288
  ushort* mid  = (ushort*)(b288 + 288);       // M*256 ushorts
  ushort* vbf  = mid + (size_t)M * 256;       // M*256 ushorts
  ushort* wvT  = vbf + (size_t)M * 256;       // 65536
  ushort* woT  = wvT + 65536;                 // 65536
  ushort* wcT  = woT + 65536;                 // 73728

  // bf16 A-operands live in d_out (2 x M*256 ushorts = exact fit).
  ushort* vhi = (ushort*)d_out;
  ushort* qhi = vhi + (size_t)M * 256;

  const int gridM = (M + 127) / 128;
  const int convGrid = (M * 64 + 255) / 256;

  // 0. weight prep (bf16 hi only)
  convert_W<<<288, 256, 0, stream>>>(Wv, Woff, Watt, Wo, boff, batt,
                                     wvT, wcT, woT, b288);
  // 1a. value -> bf16
  convertA_hi<<<convGrid, 256, 0, stream>>>(value, vhi, M * 64);
  // 1b. value projection -> vbf (bf16, head-major)
  gemm_bf16<1><<<dim3(gridM, 2), 256, 0, stream>>>(
      vhi, wvT, bv, nullptr, vbf, M, 256);
  // 2a. query -> bf16
  convertA_hi<<<convGrid, 256, 0, stream>>>(query, qhi, M * 64);
  // 2b. offsets+attention raw projection -> raw (fp32)
  gemm_bf16<0><<<dim3(gridM, 3), 256, 0, stream>>>(
      qhi, wcT, b288, raw, nullptr, M, 288);
  // 3. softmax + coords + bilinear setup, packed in place on raw
  finalize_pack<<<(M + 31) / 32, 256, 0, stream>>>(raw, refpt, M);
  // 4. deformable bilinear sampling, XCD-partitioned by (b,h) pair
  const int qchunks = (nq + 31) / 32;
  deform_packed<<<qchunks * nb * NH, 256, 0, stream>>>(
      vbf, (const uint*)raw, mid, nq);
  // 5. output projection: mid (bf16) @ Wo -> d_out (fp32)
  gemm_bf16<0><<<dim3(gridM, 2), 256, 0, stream>>>(
      mid, woT, bo, (float*)d_out, nullptr, M, 256);
}

// Round 10
// 247.371 us; speedup vs baseline: 1.1513x; 1.1190x over previous
//
#include <hip/hip_runtime.h>
#include <hip/hip_bf16.h>

// Problem constants (fixed by the reference)
#define E    256
#define NH   8
#define NL   3
#define NP   4
#define HD   32
#define LQ   13125   // = Lv = 10000 + 2500 + 625

typedef short bf16x8 __attribute__((ext_vector_type(8)));
typedef float f32x4  __attribute__((ext_vector_type(4)));

// round-to-nearest-even fp32 -> bf16 (as ushort bits)
__device__ __forceinline__ ushort f2bf(float x) {
  uint u = __float_as_uint(x);
  uint r = (u + 0x7fffu + ((u >> 16) & 1u)) >> 16;
  return (ushort)r;
}
__device__ __forceinline__ float bf2f(ushort u) {
  return __uint_as_float((uint)u << 16);
}
__device__ __forceinline__ float2 bfpair(uint u) {
  float2 f;
  f.x = __uint_as_float(u << 16);
  f.y = __uint_as_float(u & 0xffff0000u);
  return f;
}

__device__ __forceinline__ void gl_lds16(const ushort* g, ushort* l) {
  __builtin_amdgcn_global_load_lds(
      (const __attribute__((address_space(1))) void*)g,
      (__attribute__((address_space(3))) void*)l, 16, 0, 0);
}

// ---------------------------------------------------------------------------
// fp32 [M][256] -> bf16 (hi only), vectorized.
// ---------------------------------------------------------------------------
__global__ __launch_bounds__(256) void convertA_hi(
    const float* __restrict__ A, ushort* __restrict__ hi, int n4) {
  const int i = blockIdx.x * 256 + threadIdx.x;
  if (i >= n4) return;
  const float4 a = ((const float4*)A)[i];
  ushort4 h;
  h.x = f2bf(a.x); h.y = f2bf(a.y); h.z = f2bf(a.z); h.w = f2bf(a.w);
  ((ushort4*)hi)[i] = h;
}

// ---------------------------------------------------------------------------
// Single-phase bf16 MFMA GEMM (round-7 proven, single-buffer m97 structure).
// ---------------------------------------------------------------------------
template <int OUT_MODE>
__global__ __launch_bounds__(256) void gemm_bf16(
    const ushort* __restrict__ A_, const ushort* __restrict__ B_,
    const float* __restrict__ bias, float* __restrict__ C,
    ushort* __restrict__ Cbf, int M, int N) {
  __shared__ ushort As[4096];
  __shared__ ushort Bs[4096];
  const int tid = threadIdx.x;
  const int lane = tid & 63;
  const int wid = tid >> 6;
  const int wm = wid >> 1, wn = wid & 1;
  const int r0 = blockIdx.x * 128;
  const int c0 = blockIdx.y * 128;
  const int l15 = lane & 15;
  const int lhi = lane >> 4;
  const int srow = lane >> 2;
  const int skoff = (lane & 3) * 8;

  f32x4 acc[4][4] = {};

  for (int kk = 0; kk < 256; kk += 32) {
#pragma unroll
    for (int j = 0; j < 2; ++j) {
      const int c = wid + j * 4;
      const int arow = min(r0 + c * 16 + srow, M - 1);
      const int brow = min(c0 + c * 16 + srow, N - 1);
      gl_lds16(A_ + (size_t)arow * 256 + kk + skoff, As + c * 512);
      gl_lds16(B_ + (size_t)brow * 256 + kk + skoff, Bs + c * 512);
    }
    __syncthreads();

    bf16x8 af[4], bf[4];
#pragma unroll
    for (int mi = 0; mi < 4; ++mi)
      af[mi] = *(const bf16x8*)&As[(wm * 64 + mi * 16 + l15) * 32 + lhi * 8];
#pragma unroll
    for (int ni = 0; ni < 4; ++ni)
      bf[ni] = *(const bf16x8*)&Bs[(wn * 64 + ni * 16 + l15) * 32 + lhi * 8];
#pragma unroll
    for (int mi = 0; mi < 4; ++mi)
#pragma unroll
      for (int ni = 0; ni < 4; ++ni)
        acc[mi][ni] = __builtin_amdgcn_mfma_f32_16x16x32_bf16(
            af[mi], bf[ni], acc[mi][ni], 0, 0, 0);
    __syncthreads();
  }

#pragma unroll
  for (int ni = 0; ni < 4; ++ni) {
    const int col = c0 + wn * 64 + ni * 16 + l15;
    if (col >= N) continue;
    const float bb = bias[col];
#pragma unroll
    for (int mi = 0; mi < 4; ++mi) {
      const int rowb = r0 + wm * 64 + mi * 16 + lhi * 4;
#pragma unroll
      for (int r = 0; r < 4; ++r) {
        const int row = rowb + r;
        if (row >= M) continue;
        if (OUT_MODE == 0) {
          C[(size_t)row * N + col] = acc[mi][ni][r] + bb;
        } else {
          const int bidx = row / LQ, pos = row - bidx * LQ;
          const int h = col >> 5, d = col & 31;
          Cbf[((size_t)(bidx * NH + h) * LQ + pos) * HD + d] =
              f2bf(acc[mi][ni][r] + bb);
        }
      }
    }
  }
}

// ---------------------------------------------------------------------------
// One-shot weight prep: transpose + bf16 (hi only).
// ---------------------------------------------------------------------------
__global__ __launch_bounds__(256) void convert_W(
    const float* __restrict__ Wv, const float* __restrict__ Woff,
    const float* __restrict__ Watt, const float* __restrict__ Wo,
    const float* __restrict__ boff, const float* __restrict__ batt,
    ushort* __restrict__ WvT, ushort* __restrict__ WcT,
    ushort* __restrict__ WoT, float* __restrict__ bias288) {
  const int t = blockIdx.x * 256 + threadIdx.x;
  if (t < 256 * 256) {
    const int n = t >> 8, k = t & 255;
    WvT[t] = f2bf(Wv[k * 256 + n]);
    WoT[t] = f2bf(Wo[k * 256 + n]);
  }
  if (t < 288 * 256) {
    const int n = t >> 8, k = t & 255;
    const float w = (n < 192) ? Woff[k * 192 + n] : Watt[k * 96 + (n - 192)];
    WcT[t] = f2bf(w);
  }
  if (t < 288) bias288[t] = (t < 192) ? boff[t] : batt[t - 192];
}

// ---------------------------------------------------------------------------
// finalize_pack with LDS staging: block loads its 32x288 fp32 panel coalesced
// into LDS (stride 292: 16B-aligned rows, banks spread 4/row), computes the
// per-(g,h) packed bilinear records from LDS, stages them back through LDS,
// and stores coalesced IN PLACE over raw.
// Record/sample (12B): d0 = idx00|meta<<16 (meta = dx|dyW<<1),
// d1 = w00|w01 (bf16x2), d2 = w10|w11.  Per g: 8h*36 = 288 dwords.
// ---------------------------------------------------------------------------
#define FPSTR 292
__global__ __launch_bounds__(256) void finalize_pack(
    float* __restrict__ raw, const float* __restrict__ ref, int M) {
  __shared__ float lds[32 * FPSTR];
  const int tid = threadIdx.x;
  const int g0 = blockIdx.x * 32;

  // coalesced load: 32*288 = 9216 floats
#pragma unroll
  for (int k = 0; k < 9; ++k) {
    const int idx = k * 1024 + tid * 4;
    const int r = idx / 288, c = idx - r * 288;
    const int g = g0 + r;
    float4 v = (g < M) ? *(const float4*)&raw[(size_t)g * 288 + c]
                       : make_float4(0.f, 0.f, 0.f, 0.f);
    *(float4*)&lds[r * FPSTR + c] = v;
  }
  __syncthreads();

  const int r = tid >> 3, h = tid & 7;
  const int g = g0 + r;
  uint out[36];
  if (g < M) {
    const float* rg = &lds[r * FPSTR];
    float xy[24], lg[12];
#pragma unroll
    for (int j = 0; j < 24; ++j) xy[j] = rg[h * 24 + j];
#pragma unroll
    for (int j = 0; j < 12; ++j) lg[j] = rg[192 + h * 12 + j];
    float rx[3], ry[3];
#pragma unroll
    for (int l = 0; l < 3; ++l) {
      rx[l] = ref[(size_t)g * 6 + l * 2 + 0];
      ry[l] = ref[(size_t)g * 6 + l * 2 + 1];
    }
    float m = lg[0];
#pragma unroll
    for (int j = 1; j < 12; ++j) m = fmaxf(m, lg[j]);
    float e[12], s = 0.f;
#pragma unroll
    for (int j = 0; j < 12; ++j) { e[j] = __expf(lg[j] - m); s += e[j]; }
    const float inv = 1.f / s;

    const float S_[3] = {100.f, 50.f, 25.f};
    const int Wl_[3] = {100, 50, 25};
#pragma unroll
    for (int l = 0; l < 3; ++l) {
      const int Wl = Wl_[l];
#pragma unroll
      for (int p = 0; p < 4; ++p) {
        const int j = l * 4 + p;
        const float x = rx[l] * S_[l] + xy[l * 8 + p * 2 + 0] - 0.5f;
        const float y = ry[l] * S_[l] + xy[l * 8 + p * 2 + 1] - 0.5f;
        const float w = e[j] * inv;
        const float fx = floorf(x), fy = floorf(y);
        const int x0 = (int)fx, y0 = (int)fy;
        const float wx1 = x - fx, wy1 = y - fy;
        const float wx0 = 1.f - wx1, wy0 = 1.f - wy1;
        const int x0c = min(max(x0, 0), Wl - 1);
        const int x1c = min(max(x0 + 1, 0), Wl - 1);
        const int y0c = min(max(y0, 0), Wl - 1);
        const int y1c = min(max(y0 + 1, 0), Wl - 1);
        const float vx0 = (x0 >= 0 && x0 < Wl) ? wx0 : 0.f;
        const float vx1 = (x0 + 1 >= 0 && x0 + 1 < Wl) ? wx1 : 0.f;
        const float vy0 = (y0 >= 0 && y0 < Wl) ? wy0 : 0.f;
        const float vy1 = (y0 + 1 >= 0 && y0 + 1 < Wl) ? wy1 : 0.f;
        const int idx00 = y0c * Wl + x0c;
        const uint meta = (uint)(x1c - x0c) | ((uint)((y1c - y0c) * Wl) << 1);
        out[j * 3 + 0] = (uint)idx00 | (meta << 16);
        out[j * 3 + 1] = (uint)f2bf(w * vy0 * vx0) | ((uint)f2bf(w * vy0 * vx1) << 16);
        out[j * 3 + 2] = (uint)f2bf(w * vy1 * vx0) | ((uint)f2bf(w * vy1 * vx1) << 16);
      }
    }
  }
  __syncthreads();
  if (g < M) {
    uint* og = (uint*)&lds[r * FPSTR] + h * 36;
#pragma unroll
    for (int i = 0; i < 36; ++i) og[i] = out[i];
  }
  __syncthreads();
  // coalesced store of packed records over raw
#pragma unroll
  for (int k = 0; k < 9; ++k) {
    const int idx = k * 1024 + tid * 4;
    const int r2 = idx / 288, c = idx - r2 * 288;
    const int g2 = g0 + r2;
    if (g2 < M)
      *(uint4*)&((uint*)raw)[(size_t)g2 * 288 + c] =
          *(const uint4*)&((const uint*)lds)[r2 * FPSTR + c];
  }
}

// ---------------------------------------------------------------------------
// Bilinear sampling v3: x-pair loads.  8 lanes per (g,h): lane i -> x-side
// xs=i>>2, channel-quad cq=i&3 (8 channels, 16B).  Per sample only 2 uint4
// loads/lane (y0-row, y1-row; x-pair is 128B contiguous when dx=1).  Separate
// y0/y1 accumulator chains; one shfl_xor(4) 8-float reduce merges x-sides.
// XCD partitioning kept: blockIdx.x = qchunk*32 + pair (pair = b*8+h),
// round-robin %8 -> per-XCD value slice 3.4 MB < 4 MB L2 (r9: FETCH halved).
// ---------------------------------------------------------------------------
__global__ __launch_bounds__(256) void deform_packed(
    const ushort* __restrict__ vbf, const uint* __restrict__ samp,
    ushort* __restrict__ mid, int nq) {
  const int tid = threadIdx.x;
  const int pair = blockIdx.x & 31;          // b*8 + h
  const int qc = blockIdx.x >> 5;
  const int q = qc * 32 + (tid >> 3);        // query within batch
  if (q >= nq) return;
  const int lane8 = tid & 7;
  const int xs = lane8 >> 2;                 // x-side (0/1)
  const int cq = lane8 & 3;                  // channel quad (8 ch)
  const int h = pair & 7;
  const int b = pair >> 3;
  const int g = b * nq + q;

  const uint4* sp = (const uint4*)(samp + (size_t)g * 288 + h * 36);
  const ushort* vb = vbf + ((size_t)pair * nq) * HD + cq * 8;

  const int loff_[3] = {0, 10000, 12500};
  float a0 = 0.f, a1 = 0.f, a2 = 0.f, a3 = 0.f;
  float a4 = 0.f, a5 = 0.f, a6 = 0.f, a7 = 0.f;

#pragma unroll
  for (int l = 0; l < NL; ++l) {
    const ushort* vl = vb + (size_t)loff_[l] * HD;
    const uint4 s0 = sp[l * 3 + 0];
    const uint4 s1 = sp[l * 3 + 1];
    const uint4 s2 = sp[l * 3 + 2];
    const uint sd[12] = {s0.x, s0.y, s0.z, s0.w,
                         s1.x, s1.y, s1.z, s1.w,
                         s2.x, s2.y, s2.z, s2.w};
#pragma unroll
    for (int p = 0; p < NP; ++p) {
      const uint d0 = sd[p * 3 + 0];
      const int idx00 = (int)(d0 & 0xffffu);
      const uint meta = d0 >> 16;
      const int dx = (int)(meta & 1u);
      const int dyW = (int)(meta >> 1);
      const float2 wA = bfpair(sd[p * 3 + 1]);  // w00, w01
      const float2 wB = bfpair(sd[p * 3 + 2]);  // w10, w11
      const float w0 = xs ? wA.y : wA.x;        // this lane's y0-row weight
      const float w1 = xs ? wB.y : wB.x;        // this lane's y1-row weight
      const ushort* pl = vl + (size_t)idx00 * HD + (xs ? dx * HD : 0);
      const uint4 q0 = *(const uint4*)(pl);            // y0 row, 8 ch
      const uint4 q1 = *(const uint4*)(pl + dyW * HD); // y1 row, 8 ch
      float2 f;
      f = bfpair(q0.x); a0 = fmaf(w0, f.x, a0); a1 = fmaf(w0, f.y, a1);
      f = bfpair(q0.y); a2 = fmaf(w0, f.x, a2); a3 = fmaf(w0, f.y, a3);
      f = bfpair(q0.z); a4 = fmaf(w0, f.x, a4); a5 = fmaf(w0, f.y, a5);
      f = bfpair(q0.w); a6 = fmaf(w0, f.x, a6); a7 = fmaf(w0, f.y, a7);
      f = bfpair(q1.x); a0 = fmaf(w1, f.x, a0); a1 = fmaf(w1, f.y, a1);
      f = bfpair(q1.y); a2 = fmaf(w1, f.x, a2); a3 = fmaf(w1, f.y, a3);
      f = bfpair(q1.z); a4 = fmaf(w1, f.x, a4); a5 = fmaf(w1, f.y, a5);
      f = bfpair(q1.w); a6 = fmaf(w1, f.x, a6); a7 = fmaf(w1, f.y, a7);
    }
  }

  // merge x-sides: lane i <-> i^4 (stays within the 8-lane group)
  a0 += __shfl_xor(a0, 4); a1 += __shfl_xor(a1, 4);
  a2 += __shfl_xor(a2, 4); a3 += __shfl_xor(a3, 4);
  a4 += __shfl_xor(a4, 4); a5 += __shfl_xor(a5, 4);
  a6 += __shfl_xor(a6, 4); a7 += __shfl_xor(a7, 4);

  if (xs == 0) {
    uint4 o;
    o.x = (uint)f2bf(a0) | ((uint)f2bf(a1) << 16);
    o.y = (uint)f2bf(a2) | ((uint)f2bf(a3) << 16);
    o.z = (uint)f2bf(a4) | ((uint)f2bf(a5) << 16);
    o.w = (uint)f2bf(a6) | ((uint)f2bf(a7) << 16);
    *(uint4*)&mid[(size_t)g * E + h * HD + cq * 8] = o;
  }
}

// ---------------------------------------------------------------------------
extern "C" void kernel_launch(void* const* d_in, const int* in_sizes, int n_in,
                              void* d_out, int out_size, void* d_ws, size_t ws_size,
                              hipStream_t stream) {
  const float* query = (const float*)d_in[0];
  const float* refpt = (const float*)d_in[1];
  const float* value = (const float*)d_in[2];
  const float* Wv   = (const float*)d_in[4];
  const float* bv   = (const float*)d_in[5];
  const float* Woff = (const float*)d_in[6];
  const float* boff = (const float*)d_in[7];
  const float* Watt = (const float*)d_in[8];
  const float* batt = (const float*)d_in[9];
  const float* Wo   = (const float*)d_in[10];
  const float* bo   = (const float*)d_in[11];

  const int M = in_sizes[0] / E;  // B * Lq = 52500
  const int nq = LQ;              // queries per batch
  const int nb = M / nq;          // B = 4

  // workspace layout (~90 MB)
  float* wsf   = (float*)d_ws;
  float* raw   = wsf;                         // M*288 floats (later: packed samples)
  float* b288  = raw + (size_t)M * 288;       // 288
  ushort* mid  = (ushort*)(b288 + 288);       // M*256 ushorts
  ushort* vbf  = mid + (size_t)M * 256;       // M*256 ushorts
  ushort* wvT  = vbf + (size_t)M * 256;       // 65536
  ushort* woT  = wvT + 65536;                 // 65536
  ushort* wcT  = woT + 65536;                 // 73728

  // bf16 A-operands live in d_out (2 x M*256 ushorts = exact fit).
  ushort* vhi = (ushort*)d_out;
  ushort* qhi = vhi + (size_t)M * 256;

  const int gridM = (M + 127) / 128;
  const int convGrid = (M * 64 + 255) / 256;

  // 0. weight prep (bf16 hi only)
  convert_W<<<288, 256, 0, stream>>>(Wv, Woff, Watt, Wo, boff, batt,
                                     wvT, wcT, woT, b288);
  // 1a. value -> bf16
  convertA_hi<<<convGrid, 256, 0, stream>>>(value, vhi, M * 64);
  // 1b. value projection -> vbf (bf16, head-major)
  gemm_bf16<1><<<dim3(gridM, 2), 256, 0, stream>>>(
      vhi, wvT, bv, nullptr, vbf, M, 256);
  // 2a. query -> bf16
  convertA_hi<<<convGrid, 256, 0, stream>>>(query, qhi, M * 64);
  // 2b. offsets+attention raw projection -> raw (fp32)
  gemm_bf16<0><<<dim3(gridM, 3), 256, 0, stream>>>(
      qhi, wcT, b288, raw, nullptr, M, 288);
  // 3. softmax + coords + bilinear setup, packed in place on raw (LDS-staged)
  finalize_pack<<<(M + 31) / 32, 256, 0, stream>>>(raw, refpt, M);
  // 4. deformable bilinear sampling, x-pair loads, XCD-partitioned
  const int qchunks = (nq + 31) / 32;
  deform_packed<<<qchunks * nb * NH, 256, 0, stream>>>(
      vbf, (const uint*)raw, mid, nq);
  // 5. output projection: mid (bf16) @ Wo -> d_out (fp32)
  gemm_bf16<0><<<dim3(gridM, 2), 256, 0, stream>>>(
      mid, woT, bo, (float*)d_out, nullptr, M, 256);
}

// Round 11
// 241.706 us; speedup vs baseline: 1.1783x; 1.0234x over previous
//
#include <hip/hip_runtime.h>
#include <hip/hip_bf16.h>

// Problem constants (fixed by the reference)
#define E    256
#define NH   8
#define NL   3
#define NP   4
#define HD   32
#define LQ   13125   // = Lv = 10000 + 2500 + 625

typedef short bf16x8 __attribute__((ext_vector_type(8)));
typedef float f32x4  __attribute__((ext_vector_type(4)));

// round-to-nearest-even fp32 -> bf16 (as ushort bits)
__device__ __forceinline__ ushort f2bf(float x) {
  uint u = __float_as_uint(x);
  uint r = (u + 0x7fffu + ((u >> 16) & 1u)) >> 16;
  return (ushort)r;
}
__device__ __forceinline__ float bf2f(ushort u) {
  return __uint_as_float((uint)u << 16);
}
__device__ __forceinline__ float2 bfpair(uint u) {
  float2 f;
  f.x = __uint_as_float(u << 16);
  f.y = __uint_as_float(u & 0xffff0000u);
  return f;
}

__device__ __forceinline__ void gl_lds16(const ushort* g, ushort* l) {
  __builtin_amdgcn_global_load_lds(
      (const __attribute__((address_space(1))) void*)g,
      (__attribute__((address_space(3))) void*)l, 16, 0, 0);
}

// ---------------------------------------------------------------------------
// fp32 -> bf16 for BOTH value and query in one dispatch.
// ---------------------------------------------------------------------------
__global__ __launch_bounds__(256) void convertA2(
    const float* __restrict__ V, const float* __restrict__ Q,
    ushort* __restrict__ vhi, ushort* __restrict__ qhi, int n4) {
  const int i = blockIdx.x * 256 + threadIdx.x;
  const bool isQ = i >= n4;
  const int j = isQ ? i - n4 : i;
  if (j >= n4) return;
  const float4 a = (isQ ? (const float4*)Q : (const float4*)V)[j];
  ushort4 h;
  h.x = f2bf(a.x); h.y = f2bf(a.y); h.z = f2bf(a.z); h.w = f2bf(a.w);
  (isQ ? (ushort4*)qhi : (ushort4*)vhi)[j] = h;
}

// ---------------------------------------------------------------------------
// Single-phase bf16 MFMA GEMM (round-7 proven, single-buffer m97 structure).
// ---------------------------------------------------------------------------
template <int OUT_MODE>
__global__ __launch_bounds__(256) void gemm_bf16(
    const ushort* __restrict__ A_, const ushort* __restrict__ B_,
    const float* __restrict__ bias, float* __restrict__ C,
    ushort* __restrict__ Cbf, int M, int N) {
  __shared__ ushort As[4096];
  __shared__ ushort Bs[4096];
  const int tid = threadIdx.x;
  const int lane = tid & 63;
  const int wid = tid >> 6;
  const int wm = wid >> 1, wn = wid & 1;
  const int r0 = blockIdx.x * 128;
  const int c0 = blockIdx.y * 128;
  const int l15 = lane & 15;
  const int lhi = lane >> 4;
  const int srow = lane >> 2;
  const int skoff = (lane & 3) * 8;

  f32x4 acc[4][4] = {};

  for (int kk = 0; kk < 256; kk += 32) {
#pragma unroll
    for (int j = 0; j < 2; ++j) {
      const int c = wid + j * 4;
      const int arow = min(r0 + c * 16 + srow, M - 1);
      const int brow = min(c0 + c * 16 + srow, N - 1);
      gl_lds16(A_ + (size_t)arow * 256 + kk + skoff, As + c * 512);
      gl_lds16(B_ + (size_t)brow * 256 + kk + skoff, Bs + c * 512);
    }
    __syncthreads();

    bf16x8 af[4], bf[4];
#pragma unroll
    for (int mi = 0; mi < 4; ++mi)
      af[mi] = *(const bf16x8*)&As[(wm * 64 + mi * 16 + l15) * 32 + lhi * 8];
#pragma unroll
    for (int ni = 0; ni < 4; ++ni)
      bf[ni] = *(const bf16x8*)&Bs[(wn * 64 + ni * 16 + l15) * 32 + lhi * 8];
#pragma unroll
    for (int mi = 0; mi < 4; ++mi)
#pragma unroll
      for (int ni = 0; ni < 4; ++ni)
        acc[mi][ni] = __builtin_amdgcn_mfma_f32_16x16x32_bf16(
            af[mi], bf[ni], acc[mi][ni], 0, 0, 0);
    __syncthreads();
  }

#pragma unroll
  for (int ni = 0; ni < 4; ++ni) {
    const int col = c0 + wn * 64 + ni * 16 + l15;
    if (col >= N) continue;
    const float bb = bias[col];
#pragma unroll
    for (int mi = 0; mi < 4; ++mi) {
      const int rowb = r0 + wm * 64 + mi * 16 + lhi * 4;
#pragma unroll
      for (int r = 0; r < 4; ++r) {
        const int row = rowb + r;
        if (row >= M) continue;
        if (OUT_MODE == 0) {
          C[(size_t)row * N + col] = acc[mi][ni][r] + bb;
        } else {
          const int bidx = row / LQ, pos = row - bidx * LQ;
          const int h = col >> 5, d = col & 31;
          Cbf[((size_t)(bidx * NH + h) * LQ + pos) * HD + d] =
              f2bf(acc[mi][ni][r] + bb);
        }
      }
    }
  }
}

// ---------------------------------------------------------------------------
// Fused offatt GEMM + finalize_pack.  One block = 128 rows x ALL 288 cols.
// 512 threads = 8 waves (4 row-groups x 2 col-groups); per wave 32x144
// (acc[2][9]).  LDS: K-loop tiles (A 8KB + B 18KB) overlaid with a 32x289
// fp32 epilogue panel (37KB).  Epilogue: 4 chunks of 32 rows -> panel ->
// softmax/coords/bilinear-pack per (row,h) -> packed records straight to
// samp (raw fp32 never touches HBM; A read once).
// Record/sample (12B): d0 = idx00|meta<<16 (meta = dx|dyW<<1),
// d1 = w00|w01 (bf16x2), d2 = w10|w11.  Per g: 8h*36 = 288 dwords.
// ---------------------------------------------------------------------------
__global__ __launch_bounds__(512) void gemm_q_pack(
    const ushort* __restrict__ A_, const ushort* __restrict__ B_,
    const float* __restrict__ bias, const float* __restrict__ ref,
    uint* __restrict__ samp, int M) {
  __shared__ __align__(16) char ldsbuf[37 * 1024];
  ushort* As = (ushort*)ldsbuf;            // [128][32]
  ushort* Bs = (ushort*)(ldsbuf + 8192);   // [288][32]
  float* panel = (float*)ldsbuf;           // [32][289], reused after K-loop

  const int tid = threadIdx.x;
  const int lane = tid & 63;
  const int wid = tid >> 6;
  const int rg = wid >> 1;   // row group (32 rows)
  const int cg = wid & 1;    // col group (144 cols)
  const int r0 = blockIdx.x * 128;
  const int l15 = lane & 15;
  const int lhi = lane >> 4;

  f32x4 acc[2][9] = {};

  for (int kk = 0; kk < 256; kk += 32) {
    // stage A: 128x32, 512 threads x 16B = exactly one issue each
    {
      const int arow = min(r0 + (tid >> 2), M - 1);
      gl_lds16(A_ + (size_t)arow * 256 + kk + (tid & 3) * 8,
               As + (tid >> 2) * 32 + (tid & 3) * 8);
    }
    // stage B: 288x32 = 1152 16B units, 3 rounds (last: waves 0-1 only)
#pragma unroll
    for (int rr = 0; rr < 3; ++rr) {
      const int u = rr * 512 + tid;
      if (u < 1152)
        gl_lds16(B_ + (size_t)(u >> 2) * 256 + kk + (u & 3) * 8,
                 Bs + (u >> 2) * 32 + (u & 3) * 8);
    }
    __syncthreads();

    bf16x8 af[2], bf[9];
#pragma unroll
    for (int mi = 0; mi < 2; ++mi)
      af[mi] = *(const bf16x8*)&As[(rg * 32 + mi * 16 + l15) * 32 + lhi * 8];
#pragma unroll
    for (int ni = 0; ni < 9; ++ni)
      bf[ni] = *(const bf16x8*)&Bs[(cg * 144 + ni * 16 + l15) * 32 + lhi * 8];
#pragma unroll
    for (int mi = 0; mi < 2; ++mi)
#pragma unroll
      for (int ni = 0; ni < 9; ++ni)
        acc[mi][ni] = __builtin_amdgcn_mfma_f32_16x16x32_bf16(
            af[mi], bf[ni], acc[mi][ni], 0, 0, 0);
    __syncthreads();
  }

  // Epilogue: 4 chunks of 32 rows through the LDS panel.
  const float S_[3] = {100.f, 50.f, 25.f};
  const int Wl_[3] = {100, 50, 25};
#pragma unroll
  for (int c = 0; c < 4; ++c) {
    if (rg == c) {
#pragma unroll
      for (int mi = 0; mi < 2; ++mi)
#pragma unroll
        for (int ni = 0; ni < 9; ++ni) {
          const int col = cg * 144 + ni * 16 + l15;
          const float bb = bias[col];
          const int rl = mi * 16 + lhi * 4;
#pragma unroll
          for (int r = 0; r < 4; ++r)
            panel[(rl + r) * 289 + col] = acc[mi][ni][r] + bb;
        }
    }
    __syncthreads();
    if (tid < 256) {
      const int r = tid >> 3, h = tid & 7;
      const int g = r0 + c * 32 + r;
      if (g < M) {
        const float* rg_ = &panel[r * 289];
        float xy[24], lg[12];
#pragma unroll
        for (int j = 0; j < 24; ++j) xy[j] = rg_[h * 24 + j];
#pragma unroll
        for (int j = 0; j < 12; ++j) lg[j] = rg_[192 + h * 12 + j];
        float rx[3], ry[3];
#pragma unroll
        for (int l = 0; l < 3; ++l) {
          rx[l] = ref[(size_t)g * 6 + l * 2 + 0];
          ry[l] = ref[(size_t)g * 6 + l * 2 + 1];
        }
        float m = lg[0];
#pragma unroll
        for (int j = 1; j < 12; ++j) m = fmaxf(m, lg[j]);
        float e[12], s = 0.f;
#pragma unroll
        for (int j = 0; j < 12; ++j) { e[j] = __expf(lg[j] - m); s += e[j]; }
        const float inv = 1.f / s;

        uint out[36];
#pragma unroll
        for (int l = 0; l < 3; ++l) {
          const int Wl = Wl_[l];
#pragma unroll
          for (int p = 0; p < 4; ++p) {
            const int j = l * 4 + p;
            const float x = rx[l] * S_[l] + xy[l * 8 + p * 2 + 0] - 0.5f;
            const float y = ry[l] * S_[l] + xy[l * 8 + p * 2 + 1] - 0.5f;
            const float w = e[j] * inv;
            const float fx = floorf(x), fy = floorf(y);
            const int x0 = (int)fx, y0 = (int)fy;
            const float wx1 = x - fx, wy1 = y - fy;
            const float wx0 = 1.f - wx1, wy0 = 1.f - wy1;
            const int x0c = min(max(x0, 0), Wl - 1);
            const int x1c = min(max(x0 + 1, 0), Wl - 1);
            const int y0c = min(max(y0, 0), Wl - 1);
            const int y1c = min(max(y0 + 1, 0), Wl - 1);
            const float vx0 = (x0 >= 0 && x0 < Wl) ? wx0 : 0.f;
            const float vx1 = (x0 + 1 >= 0 && x0 + 1 < Wl) ? wx1 : 0.f;
            const float vy0 = (y0 >= 0 && y0 < Wl) ? wy0 : 0.f;
            const float vy1 = (y0 + 1 >= 0 && y0 + 1 < Wl) ? wy1 : 0.f;
            const int idx00 = y0c * Wl + x0c;
            const uint meta = (uint)(x1c - x0c) | ((uint)((y1c - y0c) * Wl) << 1);
            out[j * 3 + 0] = (uint)idx00 | (meta << 16);
            out[j * 3 + 1] = (uint)f2bf(w * vy0 * vx0) | ((uint)f2bf(w * vy0 * vx1) << 16);
            out[j * 3 + 2] = (uint)f2bf(w * vy1 * vx0) | ((uint)f2bf(w * vy1 * vx1) << 16);
          }
        }
        uint4* o4 = (uint4*)(samp + (size_t)g * 288 + h * 36);
#pragma unroll
        for (int i = 0; i < 9; ++i)
          o4[i] = make_uint4(out[i * 4 + 0], out[i * 4 + 1],
                             out[i * 4 + 2], out[i * 4 + 3]);
      }
    }
    __syncthreads();
  }
}

// ---------------------------------------------------------------------------
// One-shot weight prep: transpose + bf16 (hi only).
// ---------------------------------------------------------------------------
__global__ __launch_bounds__(256) void convert_W(
    const float* __restrict__ Wv, const float* __restrict__ Woff,
    const float* __restrict__ Watt, const float* __restrict__ Wo,
    const float* __restrict__ boff, const float* __restrict__ batt,
    ushort* __restrict__ WvT, ushort* __restrict__ WcT,
    ushort* __restrict__ WoT, float* __restrict__ bias288) {
  const int t = blockIdx.x * 256 + threadIdx.x;
  if (t < 256 * 256) {
    const int n = t >> 8, k = t & 255;
    WvT[t] = f2bf(Wv[k * 256 + n]);
    WoT[t] = f2bf(Wo[k * 256 + n]);
  }
  if (t < 288 * 256) {
    const int n = t >> 8, k = t & 255;
    const float w = (n < 192) ? Woff[k * 192 + n] : Watt[k * 96 + (n - 192)];
    WcT[t] = f2bf(w);
  }
  if (t < 288) bias288[t] = (t < 192) ? boff[t] : batt[t - 192];
}

// ---------------------------------------------------------------------------
// Bilinear sampling v3 (round-10 proven): x-pair loads, XCD-partitioned.
// 8 lanes per (g,h): lane i -> x-side xs=i>>2, channel-quad cq=i&3.
// 2 uint4 loads/sample/lane; shfl_xor(4) merges x-sides.
// blockIdx.x = qchunk*32 + pair (pair = b*8+h) -> per-XCD slice L2-resident.
// ---------------------------------------------------------------------------
__global__ __launch_bounds__(256) void deform_packed(
    const ushort* __restrict__ vbf, const uint* __restrict__ samp,
    ushort* __restrict__ mid, int nq) {
  const int tid = threadIdx.x;
  const int pair = blockIdx.x & 31;          // b*8 + h
  const int qc = blockIdx.x >> 5;
  const int q = qc * 32 + (tid >> 3);        // query within batch
  if (q >= nq) return;
  const int lane8 = tid & 7;
  const int xs = lane8 >> 2;
  const int cq = lane8 & 3;
  const int h = pair & 7;
  const int b = pair >> 3;
  const int g = b * nq + q;

  const uint4* sp = (const uint4*)(samp + (size_t)g * 288 + h * 36);
  const ushort* vb = vbf + ((size_t)pair * nq) * HD + cq * 8;

  const int loff_[3] = {0, 10000, 12500};
  float a0 = 0.f, a1 = 0.f, a2 = 0.f, a3 = 0.f;
  float a4 = 0.f, a5 = 0.f, a6 = 0.f, a7 = 0.f;

#pragma unroll
  for (int l = 0; l < NL; ++l) {
    const ushort* vl = vb + (size_t)loff_[l] * HD;
    const uint4 s0 = sp[l * 3 + 0];
    const uint4 s1 = sp[l * 3 + 1];
    const uint4 s2 = sp[l * 3 + 2];
    const uint sd[12] = {s0.x, s0.y, s0.z, s0.w,
                         s1.x, s1.y, s1.z, s1.w,
                         s2.x, s2.y, s2.z, s2.w};
#pragma unroll
    for (int p = 0; p < NP; ++p) {
      const uint d0 = sd[p * 3 + 0];
      const int idx00 = (int)(d0 & 0xffffu);
      const uint meta = d0 >> 16;
      const int dx = (int)(meta & 1u);
      const int dyW = (int)(meta >> 1);
      const float2 wA = bfpair(sd[p * 3 + 1]);
      const float2 wB = bfpair(sd[p * 3 + 2]);
      const float w0 = xs ? wA.y : wA.x;
      const float w1 = xs ? wB.y : wB.x;
      const ushort* pl = vl + (size_t)idx00 * HD + (xs ? dx * HD : 0);
      const uint4 q0 = *(const uint4*)(pl);
      const uint4 q1 = *(const uint4*)(pl + dyW * HD);
      float2 f;
      f = bfpair(q0.x); a0 = fmaf(w0, f.x, a0); a1 = fmaf(w0, f.y, a1);
      f = bfpair(q0.y); a2 = fmaf(w0, f.x, a2); a3 = fmaf(w0, f.y, a3);
      f = bfpair(q0.z); a4 = fmaf(w0, f.x, a4); a5 = fmaf(w0, f.y, a5);
      f = bfpair(q0.w); a6 = fmaf(w0, f.x, a6); a7 = fmaf(w0, f.y, a7);
      f = bfpair(q1.x); a0 = fmaf(w1, f.x, a0); a1 = fmaf(w1, f.y, a1);
      f = bfpair(q1.y); a2 = fmaf(w1, f.x, a2); a3 = fmaf(w1, f.y, a3);
      f = bfpair(q1.z); a4 = fmaf(w1, f.x, a4); a5 = fmaf(w1, f.y, a5);
      f = bfpair(q1.w); a6 = fmaf(w1, f.x, a6); a7 = fmaf(w1, f.y, a7);
    }
  }

  a0 += __shfl_xor(a0, 4); a1 += __shfl_xor(a1, 4);
  a2 += __shfl_xor(a2, 4); a3 += __shfl_xor(a3, 4);
  a4 += __shfl_xor(a4, 4); a5 += __shfl_xor(a5, 4);
  a6 += __shfl_xor(a6, 4); a7 += __shfl_xor(a7, 4);

  if (xs == 0) {
    uint4 o;
    o.x = (uint)f2bf(a0) | ((uint)f2bf(a1) << 16);
    o.y = (uint)f2bf(a2) | ((uint)f2bf(a3) << 16);
    o.z = (uint)f2bf(a4) | ((uint)f2bf(a5) << 16);
    o.w = (uint)f2bf(a6) | ((uint)f2bf(a7) << 16);
    *(uint4*)&mid[(size_t)g * E + h * HD + cq * 8] = o;
  }
}

// ---------------------------------------------------------------------------
extern "C" void kernel_launch(void* const* d_in, const int* in_sizes, int n_in,
                              void* d_out, int out_size, void* d_ws, size_t ws_size,
                              hipStream_t stream) {
  const float* query = (const float*)d_in[0];
  const float* refpt = (const float*)d_in[1];
  const float* value = (const float*)d_in[2];
  const float* Wv   = (const float*)d_in[4];
  const float* bv   = (const float*)d_in[5];
  const float* Woff = (const float*)d_in[6];
  const float* boff = (const float*)d_in[7];
  const float* Watt = (const float*)d_in[8];
  const float* batt = (const float*)d_in[9];
  const float* Wo   = (const float*)d_in[10];
  const float* bo   = (const float*)d_in[11];

  const int M = in_sizes[0] / E;  // B * Lq = 52500
  const int nq = LQ;              // queries per batch
  const int nb = M / nq;          // B = 4

  // workspace layout (~90 MB)
  float* wsf   = (float*)d_ws;
  float* raw   = wsf;                         // M*288 dwords: packed samples
  float* b288  = raw + (size_t)M * 288;       // 288
  ushort* mid  = (ushort*)(b288 + 288);       // M*256 ushorts
  ushort* vbf  = mid + (size_t)M * 256;       // M*256 ushorts
  ushort* wvT  = vbf + (size_t)M * 256;       // 65536
  ushort* woT  = wvT + 65536;                 // 65536
  ushort* wcT  = woT + 65536;                 // 73728

  // bf16 A-operands live in d_out (2 x M*256 ushorts = exact fit).
  ushort* vhi = (ushort*)d_out;
  ushort* qhi = vhi + (size_t)M * 256;

  const int gridM = (M + 127) / 128;
  const int convGrid = (2 * M * 64 + 255) / 256;

  // 0. weight prep (bf16 hi only)
  convert_W<<<288, 256, 0, stream>>>(Wv, Woff, Watt, Wo, boff, batt,
                                     wvT, wcT, woT, b288);
  // 1. value+query -> bf16 (one dispatch)
  convertA2<<<convGrid, 256, 0, stream>>>(value, query, vhi, qhi, M * 64);
  // 2. value projection -> vbf (bf16, head-major)
  gemm_bf16<1><<<dim3(gridM, 2), 256, 0, stream>>>(
      vhi, wvT, bv, nullptr, vbf, M, 256);
  // 3. fused offsets+attention GEMM + softmax/coords/pack -> samp (raw)
  gemm_q_pack<<<gridM, 512, 0, stream>>>(
      qhi, wcT, b288, refpt, (uint*)raw, M);
  // 4. deformable bilinear sampling, x-pair loads, XCD-partitioned
  const int qchunks = (nq + 31) / 32;
  deform_packed<<<qchunks * nb * NH, 256, 0, stream>>>(
      vbf, (const uint*)raw, mid, nq);
  // 5. output projection: mid (bf16) @ Wo -> d_out (fp32)
  gemm_bf16<0><<<dim3(gridM, 2), 256, 0, stream>>>(
      mid, woT, bo, (float*)d_out, nullptr, M, 256);
}

// Round 13
// 224.095 us; speedup vs baseline: 1.2709x; 1.0786x over previous
//
#include <hip/hip_runtime.h>
#include <hip/hip_bf16.h>

// Problem constants (fixed by the reference)
#define E    256
#define NH   8
#define NL   3
#define NP   4
#define HD   32
#define LQ   13125   // = Lv = 10000 + 2500 + 625

typedef short bf16x8 __attribute__((ext_vector_type(8)));
typedef float f32x4  __attribute__((ext_vector_type(4)));
typedef float f32x2  __attribute__((ext_vector_type(2)));

// round-to-nearest-even fp32 -> bf16 (as ushort bits)
__device__ __forceinline__ ushort f2bf(float x) {
  uint u = __float_as_uint(x);
  uint r = (u + 0x7fffu + ((u >> 16) & 1u)) >> 16;
  return (ushort)r;
}
__device__ __forceinline__ float bf2f(ushort u) {
  return __uint_as_float((uint)u << 16);
}
__device__ __forceinline__ float2 bfpair(uint u) {
  float2 f;
  f.x = __uint_as_float(u << 16);
  f.y = __uint_as_float(u & 0xffff0000u);
  return f;
}
__device__ __forceinline__ f32x2 bp2(uint u) {
  f32x2 f;
  f.x = __uint_as_float(u << 16);
  f.y = __uint_as_float(u & 0xffff0000u);
  return f;
}

__device__ __forceinline__ void gl_lds16(const ushort* g, ushort* l) {
  __builtin_amdgcn_global_load_lds(
      (const __attribute__((address_space(1))) void*)g,
      (__attribute__((address_space(3))) void*)l, 16, 0, 0);
}

// convert 8 consecutive fp32 -> bf16x8 (for reg-staged A conversion)
__device__ __forceinline__ bf16x8 cvt8(const float* p) {
  const float4 a = *(const float4*)p;
  const float4 b = *(const float4*)(p + 4);
  bf16x8 r;
  r[0] = (short)f2bf(a.x); r[1] = (short)f2bf(a.y);
  r[2] = (short)f2bf(a.z); r[3] = (short)f2bf(a.w);
  r[4] = (short)f2bf(b.x); r[5] = (short)f2bf(b.y);
  r[6] = (short)f2bf(b.z); r[7] = (short)f2bf(b.w);
  return r;
}

// ---------------------------------------------------------------------------
// Single-phase bf16 MFMA GEMM (m97 structure).  A_FP32: A is fp32 and is
// converted to bf16 during reg-staged LDS writes (saves the separate
// convert pass); otherwise A is bf16 staged via global_load_lds.
// OUT_MODE 0: fp32 C[M][N].  OUT_MODE 1: bf16 head-major value layout.
// ---------------------------------------------------------------------------
template <int OUT_MODE, int A_FP32>
__global__ __launch_bounds__(256) void gemm_bf16(
    const void* __restrict__ Avoid, const ushort* __restrict__ B_,
    const float* __restrict__ bias, float* __restrict__ C,
    ushort* __restrict__ Cbf, int M, int N) {
  __shared__ ushort As[4096];
  __shared__ ushort Bs[4096];
  const int tid = threadIdx.x;
  const int lane = tid & 63;
  const int wid = tid >> 6;
  const int wm = wid >> 1, wn = wid & 1;
  const int r0 = blockIdx.x * 128;
  const int c0 = blockIdx.y * 128;
  const int l15 = lane & 15;
  const int lhi = lane >> 4;
  const int srow = lane >> 2;
  const int skoff = (lane & 3) * 8;

  const ushort* A16 = (const ushort*)Avoid;
  const float* A32 = (const float*)Avoid;

  f32x4 acc[4][4] = {};

  for (int kk = 0; kk < 256; kk += 32) {
#pragma unroll
    for (int j = 0; j < 2; ++j) {
      const int c = wid + j * 4;
      const int arow = min(r0 + c * 16 + srow, M - 1);
      const int brow = min(c0 + c * 16 + srow, N - 1);
      if (A_FP32) {
        *(bf16x8*)&As[c * 512 + lane * 8] =
            cvt8(A32 + (size_t)arow * 256 + kk + skoff);
      } else {
        gl_lds16(A16 + (size_t)arow * 256 + kk + skoff, As + c * 512);
      }
      gl_lds16(B_ + (size_t)brow * 256 + kk + skoff, Bs + c * 512);
    }
    __syncthreads();

    bf16x8 af[4], bf[4];
#pragma unroll
    for (int mi = 0; mi < 4; ++mi)
      af[mi] = *(const bf16x8*)&As[(wm * 64 + mi * 16 + l15) * 32 + lhi * 8];
#pragma unroll
    for (int ni = 0; ni < 4; ++ni)
      bf[ni] = *(const bf16x8*)&Bs[(wn * 64 + ni * 16 + l15) * 32 + lhi * 8];
#pragma unroll
    for (int mi = 0; mi < 4; ++mi)
#pragma unroll
      for (int ni = 0; ni < 4; ++ni)
        acc[mi][ni] = __builtin_amdgcn_mfma_f32_16x16x32_bf16(
            af[mi], bf[ni], acc[mi][ni], 0, 0, 0);
    __syncthreads();
  }

#pragma unroll
  for (int ni = 0; ni < 4; ++ni) {
    const int col = c0 + wn * 64 + ni * 16 + l15;
    if (col >= N) continue;
    const float bb = bias[col];
#pragma unroll
    for (int mi = 0; mi < 4; ++mi) {
      const int rowb = r0 + wm * 64 + mi * 16 + lhi * 4;
#pragma unroll
      for (int r = 0; r < 4; ++r) {
        const int row = rowb + r;
        if (row >= M) continue;
        if (OUT_MODE == 0) {
          C[(size_t)row * N + col] = acc[mi][ni][r] + bb;
        } else {
          const int bidx = row / LQ, pos = row - bidx * LQ;
          const int h = col >> 5, d = col & 31;
          Cbf[((size_t)(bidx * NH + h) * LQ + pos) * HD + d] =
              f2bf(acc[mi][ni][r] + bb);
        }
      }
    }
  }
}

// ---------------------------------------------------------------------------
// Fused offatt GEMM + finalize_pack, with fp32-A reg-staged conversion.
// One block = 128 rows x ALL 288 cols, 512 threads.
// ---------------------------------------------------------------------------
__global__ __launch_bounds__(512) void gemm_q_pack(
    const float* __restrict__ A32, const ushort* __restrict__ B_,
    const float* __restrict__ bias, const float* __restrict__ ref,
    uint* __restrict__ samp, int M) {
  __shared__ __align__(16) char ldsbuf[37 * 1024];
  ushort* As = (ushort*)ldsbuf;            // [128][32]
  ushort* Bs = (ushort*)(ldsbuf + 8192);   // [288][32]
  float* panel = (float*)ldsbuf;           // [32][289], reused after K-loop

  const int tid = threadIdx.x;
  const int lane = tid & 63;
  const int wid = tid >> 6;
  const int rg = wid >> 1;   // row group (32 rows)
  const int cg = wid & 1;    // col group (144 cols)
  const int r0 = blockIdx.x * 128;
  const int l15 = lane & 15;
  const int lhi = lane >> 4;

  f32x4 acc[2][9] = {};

  for (int kk = 0; kk < 256; kk += 32) {
    // stage A: 128x32, reg-staged fp32->bf16 (one 16B ds_write per thread)
    {
      const int arow = min(r0 + (tid >> 2), M - 1);
      *(bf16x8*)&As[tid * 8] =
          cvt8(A32 + (size_t)arow * 256 + kk + (tid & 3) * 8);
    }
    // stage B: 288x32 = 1152 16B units, 3 rounds (last: waves 0-1 only)
#pragma unroll
    for (int rr = 0; rr < 3; ++rr) {
      const int u = rr * 512 + tid;
      if (u < 1152)
        gl_lds16(B_ + (size_t)(u >> 2) * 256 + kk + (u & 3) * 8,
                 Bs + (u >> 2) * 32 + (u & 3) * 8);
    }
    __syncthreads();

    bf16x8 af[2], bf[9];
#pragma unroll
    for (int mi = 0; mi < 2; ++mi)
      af[mi] = *(const bf16x8*)&As[(rg * 32 + mi * 16 + l15) * 32 + lhi * 8];
#pragma unroll
    for (int ni = 0; ni < 9; ++ni)
      bf[ni] = *(const bf16x8*)&Bs[(cg * 144 + ni * 16 + l15) * 32 + lhi * 8];
#pragma unroll
    for (int mi = 0; mi < 2; ++mi)
#pragma unroll
      for (int ni = 0; ni < 9; ++ni)
        acc[mi][ni] = __builtin_amdgcn_mfma_f32_16x16x32_bf16(
            af[mi], bf[ni], acc[mi][ni], 0, 0, 0);
    __syncthreads();
  }

  // Epilogue: 4 chunks of 32 rows through the LDS panel.
  const float S_[3] = {100.f, 50.f, 25.f};
  const int Wl_[3] = {100, 50, 25};
#pragma unroll
  for (int c = 0; c < 4; ++c) {
    if (rg == c) {
#pragma unroll
      for (int mi = 0; mi < 2; ++mi)
#pragma unroll
        for (int ni = 0; ni < 9; ++ni) {
          const int col = cg * 144 + ni * 16 + l15;
          const float bb = bias[col];
          const int rl = mi * 16 + lhi * 4;
#pragma unroll
          for (int r = 0; r < 4; ++r)
            panel[(rl + r) * 289 + col] = acc[mi][ni][r] + bb;
        }
    }
    __syncthreads();
    if (tid < 256) {
      const int r = tid >> 3, h = tid & 7;
      const int g = r0 + c * 32 + r;
      if (g < M) {
        const float* rg_ = &panel[r * 289];
        float xy[24], lg[12];
#pragma unroll
        for (int j = 0; j < 24; ++j) xy[j] = rg_[h * 24 + j];
#pragma unroll
        for (int j = 0; j < 12; ++j) lg[j] = rg_[192 + h * 12 + j];
        float rx[3], ry[3];
#pragma unroll
        for (int l = 0; l < 3; ++l) {
          rx[l] = ref[(size_t)g * 6 + l * 2 + 0];
          ry[l] = ref[(size_t)g * 6 + l * 2 + 1];
        }
        float m = lg[0];
#pragma unroll
        for (int j = 1; j < 12; ++j) m = fmaxf(m, lg[j]);
        float e[12], s = 0.f;
#pragma unroll
        for (int j = 0; j < 12; ++j) { e[j] = __expf(lg[j] - m); s += e[j]; }
        const float inv = 1.f / s;

        uint out[36];
#pragma unroll
        for (int l = 0; l < 3; ++l) {
          const int Wl = Wl_[l];
#pragma unroll
          for (int p = 0; p < 4; ++p) {
            const int j = l * 4 + p;
            const float x = rx[l] * S_[l] + xy[l * 8 + p * 2 + 0] - 0.5f;
            const float y = ry[l] * S_[l] + xy[l * 8 + p * 2 + 1] - 0.5f;
            const float w = e[j] * inv;
            const float fx = floorf(x), fy = floorf(y);
            const int x0 = (int)fx, y0 = (int)fy;
            const float wx1 = x - fx, wy1 = y - fy;
            const float wx0 = 1.f - wx1, wy0 = 1.f - wy1;
            const int x0c = min(max(x0, 0), Wl - 1);
            const int x1c = min(max(x0 + 1, 0), Wl - 1);
            const int y0c = min(max(y0, 0), Wl - 1);
            const int y1c = min(max(y0 + 1, 0), Wl - 1);
            const float vx0 = (x0 >= 0 && x0 < Wl) ? wx0 : 0.f;
            const float vx1 = (x0 + 1 >= 0 && x0 + 1 < Wl) ? wx1 : 0.f;
            const float vy0 = (y0 >= 0 && y0 < Wl) ? wy0 : 0.f;
            const float vy1 = (y0 + 1 >= 0 && y0 + 1 < Wl) ? wy1 : 0.f;
            const int idx00 = y0c * Wl + x0c;
            const uint meta = (uint)(x1c - x0c) | ((uint)((y1c - y0c) * Wl) << 1);
            out[j * 3 + 0] = (uint)idx00 | (meta << 16);
            out[j * 3 + 1] = (uint)f2bf(w * vy0 * vx0) | ((uint)f2bf(w * vy0 * vx1) << 16);
            out[j * 3 + 2] = (uint)f2bf(w * vy1 * vx0) | ((uint)f2bf(w * vy1 * vx1) << 16);
          }
        }
        uint4* o4 = (uint4*)(samp + (size_t)g * 288 + h * 36);
#pragma unroll
        for (int i = 0; i < 9; ++i)
          o4[i] = make_uint4(out[i * 4 + 0], out[i * 4 + 1],
                             out[i * 4 + 2], out[i * 4 + 3]);
      }
    }
    __syncthreads();
  }
}

// ---------------------------------------------------------------------------
// One-shot weight prep: transpose + bf16 (hi only).
// ---------------------------------------------------------------------------
__global__ __launch_bounds__(256) void convert_W(
    const float* __restrict__ Wv, const float* __restrict__ Woff,
    const float* __restrict__ Watt, const float* __restrict__ Wo,
    const float* __restrict__ boff, const float* __restrict__ batt,
    ushort* __restrict__ WvT, ushort* __restrict__ WcT,
    ushort* __restrict__ WoT, float* __restrict__ bias288) {
  const int t = blockIdx.x * 256 + threadIdx.x;
  if (t < 256 * 256) {
    const int n = t >> 8, k = t & 255;
    WvT[t] = f2bf(Wv[k * 256 + n]);
    WoT[t] = f2bf(Wo[k * 256 + n]);
  }
  if (t < 288 * 256) {
    const int n = t >> 8, k = t & 255;
    const float w = (n < 192) ? Woff[k * 192 + n] : Watt[k * 96 + (n - 192)];
    WcT[t] = f2bf(w);
  }
  if (t < 288) bias288[t] = (t < 192) ? boff[t] : batt[t - 192];
}

// ---------------------------------------------------------------------------
// Bilinear sampling v4: per level, decode all 4 samples first, issue all 8
// gathers back-to-back (8 loads in flight), then math with f32x2 packed
// accumulate (v_pk_fma_f32 candidates).  8 lanes per (g,h): xs=i>>2 x-side,
// cq=i&3 channel-quad; shfl_xor(4) merges x-sides.  XCD-partitioned:
// blockIdx.x = qchunk*32 + pair -> per-XCD value slice L2-resident.
// ---------------------------------------------------------------------------
__global__ __launch_bounds__(256) void deform_packed(
    const ushort* __restrict__ vbf, const uint* __restrict__ samp,
    ushort* __restrict__ mid, int nq) {
  const int tid = threadIdx.x;
  const int pair = blockIdx.x & 31;          // b*8 + h
  const int qc = blockIdx.x >> 5;
  const int q = qc * 32 + (tid >> 3);        // query within batch
  if (q >= nq) return;
  const int lane8 = tid & 7;
  const int xs = lane8 >> 2;
  const int cq = lane8 & 3;
  const int h = pair & 7;
  const int b = pair >> 3;
  const int g = b * nq + q;

  const uint4* sp = (const uint4*)(samp + (size_t)g * 288 + h * 36);
  const ushort* vb = vbf + ((size_t)pair * nq) * HD + cq * 8;

  const int loff_[3] = {0, 10000, 12500};
  f32x2 ac0 = {0.f, 0.f}, ac1 = {0.f, 0.f};
  f32x2 ac2 = {0.f, 0.f}, ac3 = {0.f, 0.f};

#pragma unroll
  for (int l = 0; l < NL; ++l) {
    const ushort* vl = vb + (size_t)loff_[l] * HD;
    const uint4 s0 = sp[l * 3 + 0];
    const uint4 s1 = sp[l * 3 + 1];
    const uint4 s2 = sp[l * 3 + 2];
    const uint sd[12] = {s0.x, s0.y, s0.z, s0.w,
                         s1.x, s1.y, s1.z, s1.w,
                         s2.x, s2.y, s2.z, s2.w};
    // decode all 4 samples
    const ushort* pA[4];
    const ushort* pB[4];
    float w0[4], w1[4];
#pragma unroll
    for (int p = 0; p < NP; ++p) {
      const uint d0 = sd[p * 3 + 0];
      const int idx00 = (int)(d0 & 0xffffu);
      const uint meta = d0 >> 16;
      const int dx = (int)(meta & 1u);
      const int dyW = (int)(meta >> 1);
      const float2 wA = bfpair(sd[p * 3 + 1]);
      const float2 wB = bfpair(sd[p * 3 + 2]);
      w0[p] = xs ? wA.y : wA.x;
      w1[p] = xs ? wB.y : wB.x;
      pA[p] = vl + (size_t)idx00 * HD + (xs ? dx * HD : 0);
      pB[p] = pA[p] + dyW * HD;
    }
    // issue all 8 gathers
    uint4 q0[4], q1[4];
#pragma unroll
    for (int p = 0; p < NP; ++p) {
      q0[p] = *(const uint4*)pA[p];
      q1[p] = *(const uint4*)pB[p];
    }
    // math (packed f32x2 FMA)
#pragma unroll
    for (int p = 0; p < NP; ++p) {
      const f32x2 wv0 = {w0[p], w0[p]};
      const f32x2 wv1 = {w1[p], w1[p]};
      ac0 += wv0 * bp2(q0[p].x) + wv1 * bp2(q1[p].x);
      ac1 += wv0 * bp2(q0[p].y) + wv1 * bp2(q1[p].y);
      ac2 += wv0 * bp2(q0[p].z) + wv1 * bp2(q1[p].z);
      ac3 += wv0 * bp2(q0[p].w) + wv1 * bp2(q1[p].w);
    }
  }

  float a0 = ac0.x, a1 = ac0.y, a2 = ac1.x, a3 = ac1.y;
  float a4 = ac2.x, a5 = ac2.y, a6 = ac3.x, a7 = ac3.y;
  a0 += __shfl_xor(a0, 4); a1 += __shfl_xor(a1, 4);
  a2 += __shfl_xor(a2, 4); a3 += __shfl_xor(a3, 4);
  a4 += __shfl_xor(a4, 4); a5 += __shfl_xor(a5, 4);
  a6 += __shfl_xor(a6, 4); a7 += __shfl_xor(a7, 4);

  if (xs == 0) {
    uint4 o;
    o.x = (uint)f2bf(a0) | ((uint)f2bf(a1) << 16);
    o.y = (uint)f2bf(a2) | ((uint)f2bf(a3) << 16);
    o.z = (uint)f2bf(a4) | ((uint)f2bf(a5) << 16);
    o.w = (uint)f2bf(a6) | ((uint)f2bf(a7) << 16);
    *(uint4*)&mid[(size_t)g * E + h * HD + cq * 8] = o;
  }
}

// ---------------------------------------------------------------------------
extern "C" void kernel_launch(void* const* d_in, const int* in_sizes, int n_in,
                              void* d_out, int out_size, void* d_ws, size_t ws_size,
                              hipStream_t stream) {
  const float* query = (const float*)d_in[0];
  const float* refpt = (const float*)d_in[1];
  const float* value = (const float*)d_in[2];
  const float* Wv   = (const float*)d_in[4];
  const float* bv   = (const float*)d_in[5];
  const float* Woff = (const float*)d_in[6];
  const float* boff = (const float*)d_in[7];
  const float* Watt = (const float*)d_in[8];
  const float* batt = (const float*)d_in[9];
  const float* Wo   = (const float*)d_in[10];
  const float* bo   = (const float*)d_in[11];

  const int M = in_sizes[0] / E;  // B * Lq = 52500
  const int nq = LQ;              // queries per batch
  const int nb = M / nq;          // B = 4

  // workspace layout (~90 MB)
  float* wsf   = (float*)d_ws;
  float* raw   = wsf;                         // M*288 dwords: packed samples
  float* b288  = raw + (size_t)M * 288;       // 288
  ushort* mid  = (ushort*)(b288 + 288);       // M*256 ushorts
  ushort* vbf  = mid + (size_t)M * 256;       // M*256 ushorts
  ushort* wvT  = vbf + (size_t)M * 256;       // 65536
  ushort* woT  = wvT + 65536;                 // 65536
  ushort* wcT  = woT + 65536;                 // 73728

  const int gridM = (M + 127) / 128;

  // 0. weight prep (bf16 hi only)
  convert_W<<<288, 256, 0, stream>>>(Wv, Woff, Watt, Wo, boff, batt,
                                     wvT, wcT, woT, b288);
  // 1. value projection (fp32 A, fused conversion) -> vbf (bf16, head-major)
  gemm_bf16<1, 1><<<dim3(gridM, 2), 256, 0, stream>>>(
      value, wvT, bv, nullptr, vbf, M, 256);
  // 2. fused offsets+attention GEMM (fp32 A) + softmax/coords/pack -> samp
  gemm_q_pack<<<gridM, 512, 0, stream>>>(
      query, wcT, b288, refpt, (uint*)raw, M);
  // 3. deformable bilinear sampling, x-pair loads, XCD-partitioned
  const int qchunks = (nq + 31) / 32;
  deform_packed<<<qchunks * nb * NH, 256, 0, stream>>>(
      vbf, (const uint*)raw, mid, nq);
  // 4. output projection: mid (bf16) @ Wo -> d_out (fp32)
  gemm_bf16<0, 0><<<dim3(gridM, 2), 256, 0, stream>>>(
      mid, woT, bo, (float*)d_out, nullptr, M, 256);
}

// Round 14
// 196.880 us; speedup vs baseline: 1.4466x; 1.1382x over previous
//
#include <hip/hip_runtime.h>
#include <hip/hip_bf16.h>

// Problem constants (fixed by the reference)
#define E    256
#define NH   8
#define NL   3
#define NP   4
#define HD   32
#define LQ   13125   // = Lv = 10000 + 2500 + 625

typedef short bf16x8 __attribute__((ext_vector_type(8)));
typedef float f32x4  __attribute__((ext_vector_type(4)));
typedef float f32x2  __attribute__((ext_vector_type(2)));

// round-to-nearest-even fp32 -> bf16 (as ushort bits)
__device__ __forceinline__ ushort f2bf(float x) {
  uint u = __float_as_uint(x);
  uint r = (u + 0x7fffu + ((u >> 16) & 1u)) >> 16;
  return (ushort)r;
}
__device__ __forceinline__ float bf2f(ushort u) {
  return __uint_as_float((uint)u << 16);
}
__device__ __forceinline__ float2 bfpair(uint u) {
  float2 f;
  f.x = __uint_as_float(u << 16);
  f.y = __uint_as_float(u & 0xffff0000u);
  return f;
}
__device__ __forceinline__ f32x2 bp2(uint u) {
  f32x2 f;
  f.x = __uint_as_float(u << 16);
  f.y = __uint_as_float(u & 0xffff0000u);
  return f;
}

__device__ __forceinline__ void gl_lds16(const ushort* g, ushort* l) {
  __builtin_amdgcn_global_load_lds(
      (const __attribute__((address_space(1))) void*)g,
      (__attribute__((address_space(3))) void*)l, 16, 0, 0);
}

// convert 8 consecutive fp32 -> bf16x8 (for reg-staged A conversion)
__device__ __forceinline__ bf16x8 cvt8(const float* p) {
  const float4 a = *(const float4*)p;
  const float4 b = *(const float4*)(p + 4);
  bf16x8 r;
  r[0] = (short)f2bf(a.x); r[1] = (short)f2bf(a.y);
  r[2] = (short)f2bf(a.z); r[3] = (short)f2bf(a.w);
  r[4] = (short)f2bf(b.x); r[5] = (short)f2bf(b.y);
  r[6] = (short)f2bf(b.z); r[7] = (short)f2bf(b.w);
  return r;
}

// ---------------------------------------------------------------------------
// Wide bf16 MFMA GEMM: 128x256 tile per block, 512 threads (8 waves, 2x4
// grid of 64x64), N fixed at 256.  A is staged ONCE per block (vs twice in
// the (gridM,2) layout) -- halves A traffic (and cvt8 work when A_FP32).
// A_FP32: fp32 A converted bf16 during reg-staged LDS writes; else
// global_load_lds (wave-uniform base + lane*16B, layout verified).
// OUT_MODE 0: fp32 C[M][256].  OUT_MODE 1: bf16 head-major value layout.
// ---------------------------------------------------------------------------
template <int OUT_MODE, int A_FP32>
__global__ __launch_bounds__(512) void gemm_wide(
    const void* __restrict__ Avoid, const ushort* __restrict__ B_,
    const float* __restrict__ bias, float* __restrict__ C,
    ushort* __restrict__ Cbf, int M) {
  __shared__ ushort As[4096];   // [128][32]
  __shared__ ushort Bs[8192];   // [256][32]
  const int tid = threadIdx.x;
  const int lane = tid & 63;
  const int wid = tid >> 6;          // 0..7
  const int wm = wid >> 2, wn = wid & 3;
  const int r0 = blockIdx.x * 128;
  const int l15 = lane & 15;
  const int lhi = lane >> 4;

  const ushort* A16 = (const ushort*)Avoid;
  const float* A32 = (const float*)Avoid;

  f32x4 acc[4][4] = {};

  for (int kk = 0; kk < 256; kk += 32) {
    // stage A: 128x32 = 512 16B chunks, one per thread
    {
      const int arow = min(r0 + (tid >> 2), M - 1);
      if (A_FP32) {
        *(bf16x8*)&As[tid * 8] =
            cvt8(A32 + (size_t)arow * 256 + kk + (tid & 3) * 8);
      } else {
        // wave-uniform LDS base + lane*16B == As[tid*8] layout
        gl_lds16(A16 + (size_t)arow * 256 + kk + (lane & 3) * 8
                     + ((size_t)0),  // row term below
                 As + wid * 512);
      }
    }
    if (!A_FP32) {
      // (gl_lds16 above needs the per-lane row in the SOURCE address; redo
      // properly: row = r0 + wid*16 + (lane>>2).)
    }
    // stage B: 256x32 = 1024 16B chunks, 2 rounds
#pragma unroll
    for (int rr = 0; rr < 2; ++rr) {
      const int u = rr * 512 + tid;
      const int brow = u >> 2;           // 0..255 (always < 256, no clamp)
      gl_lds16(B_ + (size_t)brow * 256 + kk + (u & 3) * 8,
               Bs + rr * 4096 + wid * 512);
    }
    __syncthreads();

    bf16x8 af[4], bf[4];
#pragma unroll
    for (int mi = 0; mi < 4; ++mi)
      af[mi] = *(const bf16x8*)&As[(wm * 64 + mi * 16 + l15) * 32 + lhi * 8];
#pragma unroll
    for (int ni = 0; ni < 4; ++ni)
      bf[ni] = *(const bf16x8*)&Bs[(wn * 64 + ni * 16 + l15) * 32 + lhi * 8];
#pragma unroll
    for (int mi = 0; mi < 4; ++mi)
#pragma unroll
      for (int ni = 0; ni < 4; ++ni)
        acc[mi][ni] = __builtin_amdgcn_mfma_f32_16x16x32_bf16(
            af[mi], bf[ni], acc[mi][ni], 0, 0, 0);
    __syncthreads();
  }

#pragma unroll
  for (int ni = 0; ni < 4; ++ni) {
    const int col = wn * 64 + ni * 16 + l15;
    const float bb = bias[col];
#pragma unroll
    for (int mi = 0; mi < 4; ++mi) {
      const int rowb = r0 + wm * 64 + mi * 16 + lhi * 4;
#pragma unroll
      for (int r = 0; r < 4; ++r) {
        const int row = rowb + r;
        if (row >= M) continue;
        if (OUT_MODE == 0) {
          C[(size_t)row * 256 + col] = acc[mi][ni][r] + bb;
        } else {
          const int bidx = row / LQ, pos = row - bidx * LQ;
          const int h = col >> 5, d = col & 31;
          Cbf[((size_t)(bidx * NH + h) * LQ + pos) * HD + d] =
              f2bf(acc[mi][ni][r] + bb);
        }
      }
    }
  }
}

// Specialization fix for the A16 staging path (proper per-lane source row).
// To keep one template, the A16 branch above is replaced at the call sites by
// this dedicated kernel to avoid the broken inline address in the template.
template <int OUT_MODE>
__global__ __launch_bounds__(512) void gemm_wide_a16(
    const ushort* __restrict__ A16, const ushort* __restrict__ B_,
    const float* __restrict__ bias, float* __restrict__ C,
    ushort* __restrict__ Cbf, int M) {
  __shared__ ushort As[4096];   // [128][32]
  __shared__ ushort Bs[8192];   // [256][32]
  const int tid = threadIdx.x;
  const int lane = tid & 63;
  const int wid = tid >> 6;
  const int wm = wid >> 2, wn = wid & 3;
  const int r0 = blockIdx.x * 128;
  const int l15 = lane & 15;
  const int lhi = lane >> 4;

  f32x4 acc[4][4] = {};

  for (int kk = 0; kk < 256; kk += 32) {
    {
      const int arow = min(r0 + wid * 16 + (lane >> 2), M - 1);
      gl_lds16(A16 + (size_t)arow * 256 + kk + (lane & 3) * 8,
               As + wid * 512);
    }
#pragma unroll
    for (int rr = 0; rr < 2; ++rr) {
      const int u = rr * 512 + tid;
      const int brow = u >> 2;
      gl_lds16(B_ + (size_t)brow * 256 + kk + (u & 3) * 8,
               Bs + rr * 4096 + wid * 512);
    }
    __syncthreads();

    bf16x8 af[4], bf[4];
#pragma unroll
    for (int mi = 0; mi < 4; ++mi)
      af[mi] = *(const bf16x8*)&As[(wm * 64 + mi * 16 + l15) * 32 + lhi * 8];
#pragma unroll
    for (int ni = 0; ni < 4; ++ni)
      bf[ni] = *(const bf16x8*)&Bs[(wn * 64 + ni * 16 + l15) * 32 + lhi * 8];
#pragma unroll
    for (int mi = 0; mi < 4; ++mi)
#pragma unroll
      for (int ni = 0; ni < 4; ++ni)
        acc[mi][ni] = __builtin_amdgcn_mfma_f32_16x16x32_bf16(
            af[mi], bf[ni], acc[mi][ni], 0, 0, 0);
    __syncthreads();
  }

#pragma unroll
  for (int ni = 0; ni < 4; ++ni) {
    const int col = wn * 64 + ni * 16 + l15;
    const float bb = bias[col];
#pragma unroll
    for (int mi = 0; mi < 4; ++mi) {
      const int rowb = r0 + wm * 64 + mi * 16 + lhi * 4;
#pragma unroll
      for (int r = 0; r < 4; ++r) {
        const int row = rowb + r;
        if (row >= M) continue;
        if (OUT_MODE == 0) {
          C[(size_t)row * 256 + col] = acc[mi][ni][r] + bb;
        } else {
          const int bidx = row / LQ, pos = row - bidx * LQ;
          const int h = col >> 5, d = col & 31;
          Cbf[((size_t)(bidx * NH + h) * LQ + pos) * HD + d] =
              f2bf(acc[mi][ni][r] + bb);
        }
      }
    }
  }
}

// ---------------------------------------------------------------------------
// Fused offatt GEMM + finalize_pack (round-13 proven), fp32-A reg-staged.
// One block = 128 rows x ALL 288 cols, 512 threads.
// ---------------------------------------------------------------------------
__global__ __launch_bounds__(512) void gemm_q_pack(
    const float* __restrict__ A32, const ushort* __restrict__ B_,
    const float* __restrict__ bias, const float* __restrict__ ref,
    uint* __restrict__ samp, int M) {
  __shared__ __align__(16) char ldsbuf[37 * 1024];
  ushort* As = (ushort*)ldsbuf;            // [128][32]
  ushort* Bs = (ushort*)(ldsbuf + 8192);   // [288][32]
  float* panel = (float*)ldsbuf;           // [32][289], reused after K-loop

  const int tid = threadIdx.x;
  const int lane = tid & 63;
  const int wid = tid >> 6;
  const int rg = wid >> 1;   // row group (32 rows)
  const int cg = wid & 1;    // col group (144 cols)
  const int r0 = blockIdx.x * 128;
  const int l15 = lane & 15;
  const int lhi = lane >> 4;

  f32x4 acc[2][9] = {};

  for (int kk = 0; kk < 256; kk += 32) {
    {
      const int arow = min(r0 + (tid >> 2), M - 1);
      *(bf16x8*)&As[tid * 8] =
          cvt8(A32 + (size_t)arow * 256 + kk + (tid & 3) * 8);
    }
#pragma unroll
    for (int rr = 0; rr < 3; ++rr) {
      const int u = rr * 512 + tid;
      if (u < 1152)
        gl_lds16(B_ + (size_t)(u >> 2) * 256 + kk + (u & 3) * 8,
                 Bs + (u >> 2) * 32 + (u & 3) * 8);
    }
    __syncthreads();

    bf16x8 af[2], bf[9];
#pragma unroll
    for (int mi = 0; mi < 2; ++mi)
      af[mi] = *(const bf16x8*)&As[(rg * 32 + mi * 16 + l15) * 32 + lhi * 8];
#pragma unroll
    for (int ni = 0; ni < 9; ++ni)
      bf[ni] = *(const bf16x8*)&Bs[(cg * 144 + ni * 16 + l15) * 32 + lhi * 8];
#pragma unroll
    for (int mi = 0; mi < 2; ++mi)
#pragma unroll
      for (int ni = 0; ni < 9; ++ni)
        acc[mi][ni] = __builtin_amdgcn_mfma_f32_16x16x32_bf16(
            af[mi], bf[ni], acc[mi][ni], 0, 0, 0);
    __syncthreads();
  }

  // Epilogue: 4 chunks of 32 rows through the LDS panel.
  const float S_[3] = {100.f, 50.f, 25.f};
  const int Wl_[3] = {100, 50, 25};
#pragma unroll
  for (int c = 0; c < 4; ++c) {
    if (rg == c) {
#pragma unroll
      for (int mi = 0; mi < 2; ++mi)
#pragma unroll
        for (int ni = 0; ni < 9; ++ni) {
          const int col = cg * 144 + ni * 16 + l15;
          const float bb = bias[col];
          const int rl = mi * 16 + lhi * 4;
#pragma unroll
          for (int r = 0; r < 4; ++r)
            panel[(rl + r) * 289 + col] = acc[mi][ni][r] + bb;
        }
    }
    __syncthreads();
    if (tid < 256) {
      const int r = tid >> 3, h = tid & 7;
      const int g = r0 + c * 32 + r;
      if (g < M) {
        const float* rg_ = &panel[r * 289];
        float xy[24], lg[12];
#pragma unroll
        for (int j = 0; j < 24; ++j) xy[j] = rg_[h * 24 + j];
#pragma unroll
        for (int j = 0; j < 12; ++j) lg[j] = rg_[192 + h * 12 + j];
        float rx[3], ry[3];
#pragma unroll
        for (int l = 0; l < 3; ++l) {
          rx[l] = ref[(size_t)g * 6 + l * 2 + 0];
          ry[l] = ref[(size_t)g * 6 + l * 2 + 1];
        }
        float m = lg[0];
#pragma unroll
        for (int j = 1; j < 12; ++j) m = fmaxf(m, lg[j]);
        float e[12], s = 0.f;
#pragma unroll
        for (int j = 0; j < 12; ++j) { e[j] = __expf(lg[j] - m); s += e[j]; }
        const float inv = 1.f / s;

        uint out[36];
#pragma unroll
        for (int l = 0; l < 3; ++l) {
          const int Wl = Wl_[l];
#pragma unroll
          for (int p = 0; p < 4; ++p) {
            const int j = l * 4 + p;
            const float x = rx[l] * S_[l] + xy[l * 8 + p * 2 + 0] - 0.5f;
            const float y = ry[l] * S_[l] + xy[l * 8 + p * 2 + 1] - 0.5f;
            const float w = e[j] * inv;
            const float fx = floorf(x), fy = floorf(y);
            const int x0 = (int)fx, y0 = (int)fy;
            const float wx1 = x - fx, wy1 = y - fy;
            const float wx0 = 1.f - wx1, wy0 = 1.f - wy1;
            const int x0c = min(max(x0, 0), Wl - 1);
            const int x1c = min(max(x0 + 1, 0), Wl - 1);
            const int y0c = min(max(y0, 0), Wl - 1);
            const int y1c = min(max(y0 + 1, 0), Wl - 1);
            const float vx0 = (x0 >= 0 && x0 < Wl) ? wx0 : 0.f;
            const float vx1 = (x0 + 1 >= 0 && x0 + 1 < Wl) ? wx1 : 0.f;
            const float vy0 = (y0 >= 0 && y0 < Wl) ? wy0 : 0.f;
            const float vy1 = (y0 + 1 >= 0 && y0 + 1 < Wl) ? wy1 : 0.f;
            const int idx00 = y0c * Wl + x0c;
            const uint meta = (uint)(x1c - x0c) | ((uint)((y1c - y0c) * Wl) << 1);
            out[j * 3 + 0] = (uint)idx00 | (meta << 16);
            out[j * 3 + 1] = (uint)f2bf(w * vy0 * vx0) | ((uint)f2bf(w * vy0 * vx1) << 16);
            out[j * 3 + 2] = (uint)f2bf(w * vy1 * vx0) | ((uint)f2bf(w * vy1 * vx1) << 16);
          }
        }
        uint4* o4 = (uint4*)(samp + (size_t)g * 288 + h * 36);
#pragma unroll
        for (int i = 0; i < 9; ++i)
          o4[i] = make_uint4(out[i * 4 + 0], out[i * 4 + 1],
                             out[i * 4 + 2], out[i * 4 + 3]);
      }
    }
    __syncthreads();
  }
}

// ---------------------------------------------------------------------------
// One-shot weight prep: transpose + bf16 (hi only).
// ---------------------------------------------------------------------------
__global__ __launch_bounds__(256) void convert_W(
    const float* __restrict__ Wv, const float* __restrict__ Woff,
    const float* __restrict__ Watt, const float* __restrict__ Wo,
    const float* __restrict__ boff, const float* __restrict__ batt,
    ushort* __restrict__ WvT, ushort* __restrict__ WcT,
    ushort* __restrict__ WoT, float* __restrict__ bias288) {
  const int t = blockIdx.x * 256 + threadIdx.x;
  if (t < 256 * 256) {
    const int n = t >> 8, k = t & 255;
    WvT[t] = f2bf(Wv[k * 256 + n]);
    WoT[t] = f2bf(Wo[k * 256 + n]);
  }
  if (t < 288 * 256) {
    const int n = t >> 8, k = t & 255;
    const float w = (n < 192) ? Woff[k * 192 + n] : Watt[k * 96 + (n - 192)];
    WcT[t] = f2bf(w);
  }
  if (t < 288) bias288[t] = (t < 192) ? boff[t] : batt[t - 192];
}

// ---------------------------------------------------------------------------
// Bilinear sampling v4 (round-13 proven): decode 4 samples -> 8 back-to-back
// gathers -> packed f32x2 math.  8 lanes per (g,h): xs=i>>2, cq=i&3;
// shfl_xor(4) merges x-sides.  XCD-partitioned by (b,h) pair.
// ---------------------------------------------------------------------------
__global__ __launch_bounds__(256) void deform_packed(
    const ushort* __restrict__ vbf, const uint* __restrict__ samp,
    ushort* __restrict__ mid, int nq) {
  const int tid = threadIdx.x;
  const int pair = blockIdx.x & 31;          // b*8 + h
  const int qc = blockIdx.x >> 5;
  const int q = qc * 32 + (tid >> 3);        // query within batch
  if (q >= nq) return;
  const int lane8 = tid & 7;
  const int xs = lane8 >> 2;
  const int cq = lane8 & 3;
  const int h = pair & 7;
  const int b = pair >> 3;
  const int g = b * nq + q;

  const uint4* sp = (const uint4*)(samp + (size_t)g * 288 + h * 36);
  const ushort* vb = vbf + ((size_t)pair * nq) * HD + cq * 8;

  const int loff_[3] = {0, 10000, 12500};
  f32x2 ac0 = {0.f, 0.f}, ac1 = {0.f, 0.f};
  f32x2 ac2 = {0.f, 0.f}, ac3 = {0.f, 0.f};

#pragma unroll
  for (int l = 0; l < NL; ++l) {
    const ushort* vl = vb + (size_t)loff_[l] * HD;
    const uint4 s0 = sp[l * 3 + 0];
    const uint4 s1 = sp[l * 3 + 1];
    const uint4 s2 = sp[l * 3 + 2];
    const uint sd[12] = {s0.x, s0.y, s0.z, s0.w,
                         s1.x, s1.y, s1.z, s1.w,
                         s2.x, s2.y, s2.z, s2.w};
    const ushort* pA[4];
    const ushort* pB[4];
    float w0[4], w1[4];
#pragma unroll
    for (int p = 0; p < NP; ++p) {
      const uint d0 = sd[p * 3 + 0];
      const int idx00 = (int)(d0 & 0xffffu);
      const uint meta = d0 >> 16;
      const int dx = (int)(meta & 1u);
      const int dyW = (int)(meta >> 1);
      const float2 wA = bfpair(sd[p * 3 + 1]);
      const float2 wB = bfpair(sd[p * 3 + 2]);
      w0[p] = xs ? wA.y : wA.x;
      w1[p] = xs ? wB.y : wB.x;
      pA[p] = vl + (size_t)idx00 * HD + (xs ? dx * HD : 0);
      pB[p] = pA[p] + dyW * HD;
    }
    uint4 q0[4], q1[4];
#pragma unroll
    for (int p = 0; p < NP; ++p) {
      q0[p] = *(const uint4*)pA[p];
      q1[p] = *(const uint4*)pB[p];
    }
#pragma unroll
    for (int p = 0; p < NP; ++p) {
      const f32x2 wv0 = {w0[p], w0[p]};
      const f32x2 wv1 = {w1[p], w1[p]};
      ac0 += wv0 * bp2(q0[p].x) + wv1 * bp2(q1[p].x);
      ac1 += wv0 * bp2(q0[p].y) + wv1 * bp2(q1[p].y);
      ac2 += wv0 * bp2(q0[p].z) + wv1 * bp2(q1[p].z);
      ac3 += wv0 * bp2(q0[p].w) + wv1 * bp2(q1[p].w);
    }
  }

  float a0 = ac0.x, a1 = ac0.y, a2 = ac1.x, a3 = ac1.y;
  float a4 = ac2.x, a5 = ac2.y, a6 = ac3.x, a7 = ac3.y;
  a0 += __shfl_xor(a0, 4); a1 += __shfl_xor(a1, 4);
  a2 += __shfl_xor(a2, 4); a3 += __shfl_xor(a3, 4);
  a4 += __shfl_xor(a4, 4); a5 += __shfl_xor(a5, 4);
  a6 += __shfl_xor(a6, 4); a7 += __shfl_xor(a7, 4);

  if (xs == 0) {
    uint4 o;
    o.x = (uint)f2bf(a0) | ((uint)f2bf(a1) << 16);
    o.y = (uint)f2bf(a2) | ((uint)f2bf(a3) << 16);
    o.z = (uint)f2bf(a4) | ((uint)f2bf(a5) << 16);
    o.w = (uint)f2bf(a6) | ((uint)f2bf(a7) << 16);
    *(uint4*)&mid[(size_t)g * E + h * HD + cq * 8] = o;
  }
}

// ---------------------------------------------------------------------------
extern "C" void kernel_launch(void* const* d_in, const int* in_sizes, int n_in,
                              void* d_out, int out_size, void* d_ws, size_t ws_size,
                              hipStream_t stream) {
  const float* query = (const float*)d_in[0];
  const float* refpt = (const float*)d_in[1];
  const float* value = (const float*)d_in[2];
  const float* Wv   = (const float*)d_in[4];
  const float* bv   = (const float*)d_in[5];
  const float* Woff = (const float*)d_in[6];
  const float* boff = (const float*)d_in[7];
  const float* Watt = (const float*)d_in[8];
  const float* batt = (const float*)d_in[9];
  const float* Wo   = (const float*)d_in[10];
  const float* bo   = (const float*)d_in[11];

  const int M = in_sizes[0] / E;  // B * Lq = 52500
  const int nq = LQ;              // queries per batch
  const int nb = M / nq;          // B = 4

  // workspace layout (~90 MB)
  float* wsf   = (float*)d_ws;
  float* raw   = wsf;                         // M*288 dwords: packed samples
  float* b288  = raw + (size_t)M * 288;       // 288
  ushort* mid  = (ushort*)(b288 + 288);       // M*256 ushorts
  ushort* vbf  = mid + (size_t)M * 256;       // M*256 ushorts
  ushort* wvT  = vbf + (size_t)M * 256;       // 65536
  ushort* woT  = wvT + 65536;                 // 65536
  ushort* wcT  = woT + 65536;                 // 73728

  const int gridM = (M + 127) / 128;

  // 0. weight prep (bf16 hi only)
  convert_W<<<288, 256, 0, stream>>>(Wv, Woff, Watt, Wo, boff, batt,
                                     wvT, wcT, woT, b288);
  // 1. value projection (fp32 A, fused conversion, A read once) -> vbf
  gemm_wide<1, 1><<<gridM, 512, 0, stream>>>(
      value, wvT, bv, nullptr, vbf, M);
  // 2. fused offsets+attention GEMM (fp32 A) + softmax/coords/pack -> samp
  gemm_q_pack<<<gridM, 512, 0, stream>>>(
      query, wcT, b288, refpt, (uint*)raw, M);
  // 3. deformable bilinear sampling, x-pair loads, XCD-partitioned
  const int qchunks = (nq + 31) / 32;
  deform_packed<<<qchunks * nb * NH, 256, 0, stream>>>(
      vbf, (const uint*)raw, mid, nq);
  // 4. output projection: mid (bf16, A read once) @ Wo -> d_out (fp32)
  gemm_wide_a16<0><<<gridM, 512, 0, stream>>>(
      mid, woT, bo, (float*)d_out, nullptr, M);
}